// Round 2
// baseline (33845.862 us; speedup 1.0000x reference)
//
#include <hip/hip_runtime.h>
#include <hip/hip_bf16.h>
#include <math.h>

// ---------------------------------------------------------------------------
// Direct conv, OIHW weights. One thread = one output element (NCHW).
// Requires (Hout*Wout) % 256 == 0 so `co` is uniform per 256-thread block
// (lets us stage this co's weight slice in LDS).
// ---------------------------------------------------------------------------
template<int CIN, int K, int S, int PAD, bool RELU_IN, bool RELU_OUT, bool HAS_RES>
__global__ __launch_bounds__(256)
void conv2d_k(const float* __restrict__ in, const float* __restrict__ w,
              const float* __restrict__ bias, const float* __restrict__ res,
              float* __restrict__ out,
              int Cout, int Hin, int Win, int Hout, int Wout) {
    constexpr int WSZ = CIN * K * K;
    __shared__ float sW[WSZ];
    const int hw = Hout * Wout;
    int idx = blockIdx.x * 256 + threadIdx.x;
    int co = (idx / hw) % Cout;            // uniform per block (hw % 256 == 0)
    for (int t = threadIdx.x; t < WSZ; t += 256) sW[t] = w[co * WSZ + t];
    __syncthreads();

    int ow = idx % Wout;
    int oh = (idx / Wout) % Hout;
    int n  = idx / (hw * Cout);
    int ih0 = oh * S - PAD, iw0 = ow * S - PAD;

    float acc[K];
    #pragma unroll
    for (int k = 0; k < K; ++k) acc[k] = 0.f;

    const float* ipn = in + (long long)(n * CIN) * (Hin * Win);
    #pragma unroll 2
    for (int c = 0; c < CIN; ++c) {
        const float* wrow = sW + c * K * K;
        const float* ipc  = ipn + c * Hin * Win;
        #pragma unroll
        for (int kh = 0; kh < K; ++kh) {
            int ih = ih0 + kh;
            if ((unsigned)ih < (unsigned)Hin) {
                const float* iprow = ipc + ih * Win;
                #pragma unroll
                for (int kw = 0; kw < K; ++kw) {
                    int iw = iw0 + kw;
                    if ((unsigned)iw < (unsigned)Win) {
                        float v = iprow[iw];
                        if (RELU_IN) v = fmaxf(v, 0.f);
                        acc[kh] = fmaf(v, wrow[kh * K + kw], acc[kh]);
                    }
                }
            }
        }
    }
    float a = bias ? bias[co] : 0.f;
    #pragma unroll
    for (int k = 0; k < K; ++k) a += acc[k];
    if (HAS_RES) a += res[idx];
    if (RELU_OUT) a = fmaxf(a, 0.f);
    out[idx] = a;
}

// ---------------------------------------------------------------------------
// ConvTranspose2d, k=4, stride=2, pad=1. Weights torch layout [Cin, Cout, 4, 4].
// out[oh] gets in[ih]*w[kh] where oh = 2*ih - 1 + kh  ->  exactly 2 ih taps.
// ---------------------------------------------------------------------------
template<int CIN, bool RELU_IN, bool RELU_OUT>
__global__ __launch_bounds__(256)
void convt2d(const float* __restrict__ in, const float* __restrict__ w,
             const float* __restrict__ bias, float* __restrict__ out,
             int Cout, int Hin, int Win) {
    __shared__ float sW[CIN * 16];
    const int Hout = Hin * 2, Wout = Win * 2;
    const int hw = Hout * Wout;
    int idx = blockIdx.x * 256 + threadIdx.x;
    int co = (idx / hw) % Cout;            // uniform per block
    for (int t = threadIdx.x; t < CIN * 16; t += 256) {
        int ci = t >> 4, k = t & 15;
        sW[t] = w[(ci * Cout + co) * 16 + k];
    }
    __syncthreads();

    int ow = idx % Wout;
    int oh = (idx / Wout) % Hout;
    int n  = idx / (hw * Cout);

    int ihA = (oh + 1) >> 1, khA = (oh + 1) - 2 * ihA;   // khA in {0,1}
    int iwA = (ow + 1) >> 1, kwA = (ow + 1) - 2 * iwA;

    float acc = bias ? bias[co] : 0.f;
    const float* ipn = in + (long long)(n * CIN) * (Hin * Win);
    #pragma unroll 2
    for (int ci = 0; ci < CIN; ++ci) {
        const float* ip = ipn + ci * Hin * Win;
        const float* wc = sW + ci * 16;
        #pragma unroll
        for (int a = 0; a < 2; ++a) {
            int ih = ihA - a;
            if ((unsigned)ih < (unsigned)Hin) {
                int kh = khA + 2 * a;
                #pragma unroll
                for (int b = 0; b < 2; ++b) {
                    int iw = iwA - b;
                    if ((unsigned)iw < (unsigned)Win) {
                        int kw = kwA + 2 * b;
                        float v = ip[ih * Win + iw];
                        if (RELU_IN) v = fmaxf(v, 0.f);
                        acc = fmaf(v, wc[kh * 4 + kw], acc);
                    }
                }
            }
        }
    }
    if (RELU_OUT) acc = fmaxf(acc, 0.f);
    out[idx] = acc;
}

// ---------------------------------------------------------------------------
// VQ: z [32,64,64,64] NCHW -> nearest of 512 codes (D=64).
// 2 points/thread; E staged in LDS in 128-code chunks (broadcast reads).
// Writes z_q, accumulates sum||z-q||^2 into stats[0], histogram into stats[1..512].
// ---------------------------------------------------------------------------
__global__ __launch_bounds__(256)
void vq_kernel(const float* __restrict__ z, const float* __restrict__ E,
               float* __restrict__ zq, float* __restrict__ stats) {
    __shared__ float sE[128 * 64];
    __shared__ float sN[128];
    __shared__ unsigned shist[512];
    __shared__ float red[256];
    const int t = threadIdx.x;
    for (int i = t; i < 512; i += 256) shist[i] = 0;

    int p0 = blockIdx.x * 512 + t;
    int p1 = p0 + 256;
    int n0 = p0 >> 12, r0 = p0 & 4095;
    int n1 = p1 >> 12, r1 = p1 & 4095;

    float za[64], zb[64];
    #pragma unroll
    for (int d = 0; d < 64; ++d) {
        za[d] = z[(n0 * 64 + d) * 4096 + r0];
        zb[d] = z[(n1 * 64 + d) * 4096 + r1];
    }

    float best0 = 3.4e38f, best1 = 3.4e38f;
    int bi0 = 0, bi1 = 0;

    for (int k0 = 0; k0 < 512; k0 += 128) {
        __syncthreads();
        for (int i = t; i < 128 * 64; i += 256) sE[i] = E[k0 * 64 + i];
        __syncthreads();
        if (t < 128) {     // per-code squared norm (rotated access: conflict-light)
            const float* e = sE + t * 64;
            float s = 0.f;
            #pragma unroll
            for (int d = 0; d < 64; ++d) { float x = e[(d + t) & 63]; s = fmaf(x, x, s); }
            sN[t] = s;
        }
        __syncthreads();
        for (int k = 0; k < 128; ++k) {
            const float4* e4 = reinterpret_cast<const float4*>(sE + (k << 6));
            float s0a = 0.f, s0b = 0.f, s1a = 0.f, s1b = 0.f;
            #pragma unroll
            for (int q = 0; q < 8; ++q) {
                float4 ea = e4[2 * q], eb = e4[2 * q + 1];
                s0a = fmaf(za[8*q+0], ea.x, s0a); s0a = fmaf(za[8*q+1], ea.y, s0a);
                s0a = fmaf(za[8*q+2], ea.z, s0a); s0a = fmaf(za[8*q+3], ea.w, s0a);
                s0b = fmaf(za[8*q+4], eb.x, s0b); s0b = fmaf(za[8*q+5], eb.y, s0b);
                s0b = fmaf(za[8*q+6], eb.z, s0b); s0b = fmaf(za[8*q+7], eb.w, s0b);
                s1a = fmaf(zb[8*q+0], ea.x, s1a); s1a = fmaf(zb[8*q+1], ea.y, s1a);
                s1a = fmaf(zb[8*q+2], ea.z, s1a); s1a = fmaf(zb[8*q+3], ea.w, s1a);
                s1b = fmaf(zb[8*q+4], eb.x, s1b); s1b = fmaf(zb[8*q+5], eb.y, s1b);
                s1b = fmaf(zb[8*q+6], eb.z, s1b); s1b = fmaf(zb[8*q+7], eb.w, s1b);
            }
            float sc0 = sN[k] - 2.f * (s0a + s0b);
            float sc1 = sN[k] - 2.f * (s1a + s1b);
            if (sc0 < best0) { best0 = sc0; bi0 = k0 + k; }
            if (sc1 < best1) { best1 = sc1; bi1 = k0 + k; }
        }
    }

    // exact distance + write q (gather from global E; E is L2-resident)
    const float* e0g = E + bi0 * 64;
    const float* e1g = E + bi1 * 64;
    float dist = 0.f;
    #pragma unroll
    for (int d = 0; d < 64; ++d) {
        float ed = e0g[d];
        float df = ed - za[d];
        dist = fmaf(df, df, dist);
        zq[(n0 * 64 + d) * 4096 + r0] = ed;
    }
    #pragma unroll
    for (int d = 0; d < 64; ++d) {
        float ed = e1g[d];
        float df = ed - zb[d];
        dist = fmaf(df, df, dist);
        zq[(n1 * 64 + d) * 4096 + r1] = ed;
    }
    atomicAdd(&shist[bi0], 1u);
    atomicAdd(&shist[bi1], 1u);

    red[t] = dist;
    __syncthreads();
    for (int s = 128; s > 0; s >>= 1) {
        if (t < s) red[t] += red[t + s];
        __syncthreads();
    }
    if (t == 0) atomicAdd(&stats[0], red[0]);
    for (int i = t; i < 512; i += 256) {
        unsigned c = shist[i];
        if (c) atomicAdd(&stats[1 + i], (float)c);
    }
}

// loss = (1+beta)*mean((q-z)^2); perplexity = exp(-sum p log(p+1e-10))
__global__ __launch_bounds__(512)
void finalize_kernel(const float* __restrict__ stats, float* __restrict__ out, int plast) {
    __shared__ float red[512];
    int t = threadIdx.x;
    float c = stats[1 + t];
    float p = c * (1.f / 131072.f);
    red[t] = p * logf(p + 1e-10f);
    __syncthreads();
    for (int s = 256; s > 0; s >>= 1) {
        if (t < s) red[t] += red[t + s];
        __syncthreads();
    }
    if (t == 0) {
        out[plast] = expf(-red[0]);
        out[0] = 7.6f * stats[0] * (1.f / 8388608.f);   // (1+6.6) * sum / (131072*64)
    }
}

// ---------------------------------------------------------------------------
extern "C" void kernel_launch(void* const* d_in, const int* in_sizes, int n_in,
                              void* d_out, int out_size, void* d_ws, size_t ws_size,
                              hipStream_t stream) {
    (void)in_sizes; (void)n_in; (void)ws_size;
    const float* x   = (const float*)d_in[0];
    const float* w1  = (const float*)d_in[1];
    const float* b1  = (const float*)d_in[2];
    const float* w2  = (const float*)d_in[3];
    const float* b2  = (const float*)d_in[4];
    const float* w3  = (const float*)d_in[5];
    const float* b3  = (const float*)d_in[6];
    const float* r0a = (const float*)d_in[7];
    const float* r0b = (const float*)d_in[8];
    const float* r1a = (const float*)d_in[9];
    const float* r1b = (const float*)d_in[10];
    const float* wp  = (const float*)d_in[11];
    const float* bp  = (const float*)d_in[12];
    const float* E   = (const float*)d_in[13];
    const float* dw1 = (const float*)d_in[14];
    const float* db1 = (const float*)d_in[15];
    const float* dr0a= (const float*)d_in[16];
    const float* dr0b= (const float*)d_in[17];
    const float* dr1a= (const float*)d_in[18];
    const float* dr1b= (const float*)d_in[19];
    const float* tw1 = (const float*)d_in[20];
    const float* tb1 = (const float*)d_in[21];
    const float* tw2 = (const float*)d_in[22];
    const float* tb2 = (const float*)d_in[23];

    float* out = (float*)d_out;
    float* ws  = (float*)d_ws;

    // ---------------- workspace layout (floats), total ~192 MiB ------------
    // P : 16,777,216 floats  [ws + 0)
    // Q : 33,554,432 floats  [ws + 16,777,216)
    // ST:        513 floats  [ws + 50,331,648)
    //
    // timeline (aliasing):
    //  conv1 : x -> Q                 (32,64,128,128)
    //  conv2 : Q -> P                 (32,128,64,64)
    //  conv3 : P -> Q[0:16.8M]        (32,128,64,64)
    //  enc res: C=Q[0:16.8M], F=Q[16.8M:21.0M]
    //  preVQ : Q -> Z=P[0:8.4M]
    //  VQ    : Z -> ZQ=Q[16.8M:25.2M], ST
    //  d1    : ZQ -> C2=P[0:16.8M]
    //  dec res: C2=P, F2=Q[0:4.2M]
    //  convT1: P -> T=Q (full 33.5M)
    //  convT2: Q -> out+1
    float* P  = ws;
    float* Q  = ws + 16777216;
    float* ST = ws + 50331648;
    float* F  = Q  + 16777216;   // encoder res temp
    float* Z  = P;               // pre-VQ output [32,64,64,64]
    float* ZQ = Q  + 16777216;   // quantized
    float* F2 = Q;               // decoder res temp

    hipMemsetAsync(ST, 0, 513 * sizeof(float), stream);

    dim3 blk(256);
    // ---- encoder ----
    conv2d_k<3,4,2,1,false,true,false><<<131072, blk, 0, stream>>>(x,  w1, b1, nullptr, Q,  64, 256, 256, 128, 128);
    conv2d_k<64,4,2,1,false,true,false><<<65536, blk, 0, stream>>>(Q,  w2, b2, nullptr, P, 128, 128, 128, 64, 64);
    conv2d_k<128,3,1,1,false,false,false><<<65536, blk, 0, stream>>>(P, w3, b3, nullptr, Q, 128, 64, 64, 64, 64);
    // res block 0 (no bias)
    conv2d_k<128,3,1,1,true,false,false><<<16384, blk, 0, stream>>>(Q, r0a, nullptr, nullptr, F, 32, 64, 64, 64, 64);
    conv2d_k<32,3,1,1,true,false,true><<<65536, blk, 0, stream>>>(F, r0b, nullptr, Q, Q, 128, 64, 64, 64, 64);
    // res block 1
    conv2d_k<128,3,1,1,true,false,false><<<16384, blk, 0, stream>>>(Q, r1a, nullptr, nullptr, F, 32, 64, 64, 64, 64);
    conv2d_k<32,3,1,1,true,false,true><<<65536, blk, 0, stream>>>(F, r1b, nullptr, Q, Q, 128, 64, 64, 64, 64);
    // pre-VQ 1x1 (consumes the res-stack's trailing relu via RELU_IN)
    conv2d_k<128,1,1,0,true,false,false><<<32768, blk, 0, stream>>>(Q, wp, bp, nullptr, Z, 64, 64, 64, 64, 64);

    // ---- VQ ----
    vq_kernel<<<256, blk, 0, stream>>>(Z, E, ZQ, ST);

    // ---- decoder ----
    conv2d_k<64,3,1,1,false,false,false><<<65536, blk, 0, stream>>>(ZQ, dw1, db1, nullptr, P, 128, 64, 64, 64, 64);
    conv2d_k<128,3,1,1,true,false,false><<<16384, blk, 0, stream>>>(P, dr0a, nullptr, nullptr, F2, 32, 64, 64, 64, 64);
    conv2d_k<32,3,1,1,true,false,true><<<65536, blk, 0, stream>>>(F2, dr0b, nullptr, P, P, 128, 64, 64, 64, 64);
    conv2d_k<128,3,1,1,true,false,false><<<16384, blk, 0, stream>>>(P, dr1a, nullptr, nullptr, F2, 32, 64, 64, 64, 64);
    conv2d_k<32,3,1,1,true,false,true><<<65536, blk, 0, stream>>>(F2, dr1b, nullptr, P, P, 128, 64, 64, 64, 64);
    // convT1 (relu on input = res-stack's trailing relu), relu on output
    convt2d<128,true,true><<<131072, blk, 0, stream>>>(P, tw1, tb1, Q, 64, 64, 64);
    // convT2 -> x_tilda at out[1..]
    convt2d<64,false,false><<<24576, blk, 0, stream>>>(Q, tw2, tb2, out + 1, 3, 128, 128);

    // ---- loss / perplexity ----
    finalize_kernel<<<1, 512, 0, stream>>>(ST, out, out_size - 1);
}

// Round 3
// 20861.653 us; speedup vs baseline: 1.6224x; 1.6224x over previous
//
#include <hip/hip_runtime.h>
#include <hip/hip_bf16.h>
#include <math.h>

// Round 2: fp32 direct convs rewritten for ILP — 2-4 outputs/thread, float4/float2
// vector loads, multi-accumulator. Root cause of 33.8ms was VGPR=8-12 kernels with
// zero memory-level parallelism (serial scalar loads at L2/L3 latency).

// ---------------- 3x3 stride-1 pad-1 conv, 4 outputs/thread -----------------
// Block handles 1024 consecutive NCHW outputs => co,n uniform (hw % 1024 == 0).
template<int CIN, bool RELU_IN, bool RELU_OUT, bool HAS_RES>
__global__ __launch_bounds__(256)
void conv3x3_v4(const float* __restrict__ in, const float* __restrict__ w,
                const float* __restrict__ bias, const float* __restrict__ res,
                float* __restrict__ out, int Cout, int H, int W) {
    __shared__ float sW[CIN * 9];
    const int hw = H * W;
    const int t = threadIdx.x;
    const int base = blockIdx.x * 1024;
    const int co = (base / hw) % Cout;
    const int n  = base / (hw * Cout);
    for (int i = t; i < CIN * 9; i += 256) sW[i] = w[co * CIN * 9 + i];
    __syncthreads();

    const int p  = (base % hw) + t * 4;   // p < hw
    const int ow = p % W;                 // multiple of 4
    const int oh = p / W;

    float a0, a1, a2, a3;
    a0 = a1 = a2 = a3 = bias ? bias[co] : 0.f;
    const float* ip = in + (long long)n * CIN * hw;

    #pragma unroll 2
    for (int c = 0; c < CIN; ++c) {
        const float* pl = ip + c * hw;
        const float* wr = sW + c * 9;
        #pragma unroll
        for (int kh = 0; kh < 3; ++kh) {
            int ih = oh + kh - 1;
            if ((unsigned)ih < (unsigned)H) {
                const float* r = pl + ih * W;
                float4 m = *reinterpret_cast<const float4*>(r + ow);
                float lf = ow > 0      ? r[ow - 1] : 0.f;
                float rt = ow + 4 < W  ? r[ow + 4] : 0.f;
                if (RELU_IN) {
                    lf = fmaxf(lf, 0.f); rt = fmaxf(rt, 0.f);
                    m.x = fmaxf(m.x, 0.f); m.y = fmaxf(m.y, 0.f);
                    m.z = fmaxf(m.z, 0.f); m.w = fmaxf(m.w, 0.f);
                }
                float w0 = wr[kh*3], w1 = wr[kh*3+1], w2 = wr[kh*3+2];
                a0 = fmaf(w0, lf,  fmaf(w1, m.x, fmaf(w2, m.y, a0)));
                a1 = fmaf(w0, m.x, fmaf(w1, m.y, fmaf(w2, m.z, a1)));
                a2 = fmaf(w0, m.y, fmaf(w1, m.z, fmaf(w2, m.w, a2)));
                a3 = fmaf(w0, m.z, fmaf(w1, m.w, fmaf(w2, rt,  a3)));
            }
        }
    }
    int oidx = base + t * 4;
    if (HAS_RES) {
        float4 rv = *reinterpret_cast<const float4*>(res + oidx);
        a0 += rv.x; a1 += rv.y; a2 += rv.z; a3 += rv.w;
    }
    if (RELU_OUT) {
        a0 = fmaxf(a0, 0.f); a1 = fmaxf(a1, 0.f);
        a2 = fmaxf(a2, 0.f); a3 = fmaxf(a3, 0.f);
    }
    *reinterpret_cast<float4*>(out + oidx) = make_float4(a0, a1, a2, a3);
}

// ---------------- 4x4 stride-2 pad-1 conv, 2 outputs/thread -----------------
// Block = 512 consecutive outputs => co,n uniform (hw % 512 == 0).
template<int CIN, bool RELU_OUT>
__global__ __launch_bounds__(256)
void conv4x4s2_v2(const float* __restrict__ in, const float* __restrict__ w,
                  const float* __restrict__ bias, float* __restrict__ out,
                  int Cout, int Hin, int Win, int Hout, int Wout) {
    __shared__ float sW[CIN * 16];
    const int hw = Hout * Wout;
    const int t = threadIdx.x;
    const int base = blockIdx.x * 512;
    const int co = (base / hw) % Cout;
    const int n  = base / (hw * Cout);
    for (int i = t; i < CIN * 16; i += 256) sW[i] = w[co * CIN * 16 + i];
    __syncthreads();

    const int p  = (base % hw) + t * 2;
    const int ow = p % Wout;              // even
    const int oh = p / Wout;
    const int ix = 2 * ow;                // multiple of 4 -> float4 aligned

    float a0, a1;
    a0 = a1 = bias ? bias[co] : 0.f;
    const int hwin = Hin * Win;
    const float* ip = in + (long long)n * CIN * hwin;

    #pragma unroll 2
    for (int c = 0; c < CIN; ++c) {
        const float* pl = ip + c * hwin;
        const float* wr = sW + c * 16;
        #pragma unroll
        for (int kh = 0; kh < 4; ++kh) {
            int ih = 2 * oh - 1 + kh;
            if ((unsigned)ih < (unsigned)Hin) {
                const float* r = pl + ih * Win;
                float lf = ix > 0        ? r[ix - 1] : 0.f;
                float4 m = *reinterpret_cast<const float4*>(r + ix);
                float rt = ix + 4 < Win  ? r[ix + 4] : 0.f;
                float w0 = wr[kh*4], w1 = wr[kh*4+1], w2 = wr[kh*4+2], w3 = wr[kh*4+3];
                a0 = fmaf(w0, lf,  fmaf(w1, m.x, fmaf(w2, m.y, fmaf(w3, m.z, a0))));
                a1 = fmaf(w0, m.y, fmaf(w1, m.z, fmaf(w2, m.w, fmaf(w3, rt,  a1))));
            }
        }
    }
    if (RELU_OUT) { a0 = fmaxf(a0, 0.f); a1 = fmaxf(a1, 0.f); }
    int oidx = base + t * 2;
    *reinterpret_cast<float2*>(out + oidx) = make_float2(a0, a1);
}

// ---------------- 1x1 conv, 4 outputs/thread --------------------------------
template<int CIN, bool RELU_IN>
__global__ __launch_bounds__(256)
void conv1x1_v4(const float* __restrict__ in, const float* __restrict__ w,
                const float* __restrict__ bias, float* __restrict__ out,
                int Cout, int hw) {
    __shared__ float sW[CIN];
    const int t = threadIdx.x;
    const int base = blockIdx.x * 1024;
    const int co = (base / hw) % Cout;
    const int n  = base / (hw * Cout);
    for (int i = t; i < CIN; i += 256) sW[i] = w[co * CIN + i];
    __syncthreads();

    const int p = (base % hw) + t * 4;
    float b = bias ? bias[co] : 0.f;
    float a0 = b, a1 = b, a2 = b, a3 = b;
    const float* ip = in + (long long)n * CIN * hw + p;
    #pragma unroll 4
    for (int c = 0; c < CIN; ++c) {
        float4 v = *reinterpret_cast<const float4*>(ip + c * hw);
        if (RELU_IN) {
            v.x = fmaxf(v.x, 0.f); v.y = fmaxf(v.y, 0.f);
            v.z = fmaxf(v.z, 0.f); v.w = fmaxf(v.w, 0.f);
        }
        float wc = sW[c];
        a0 = fmaf(wc, v.x, a0); a1 = fmaf(wc, v.y, a1);
        a2 = fmaf(wc, v.z, a2); a3 = fmaf(wc, v.w, a3);
    }
    *reinterpret_cast<float4*>(out + base + t * 4) = make_float4(a0, a1, a2, a3);
}

// ---------------- ConvTranspose2d k=4 s=2 p=1, 4 outputs/thread -------------
// w torch layout [Cin, Cout, 4, 4]. For ow=4k+j the 2 iw taps lie in
// {x0-1, x0, x0+1, x0+2} with x0 = ow>>1 (even -> aligned float2).
template<int CIN, bool RELU_IN, bool RELU_OUT>
__global__ __launch_bounds__(256)
void convt_v4(const float* __restrict__ in, const float* __restrict__ w,
              const float* __restrict__ bias, float* __restrict__ out,
              int Cout, int Hin, int Win) {
    __shared__ float sW[CIN * 16];
    const int Hout = Hin * 2, Wout = Win * 2;
    const int hw = Hout * Wout;
    const int t = threadIdx.x;
    const int base = blockIdx.x * 1024;
    const int co = (base / hw) % Cout;
    const int n  = base / (hw * Cout);
    for (int i = t; i < CIN * 16; i += 256) {
        int ci = i >> 4, k = i & 15;
        sW[i] = w[(ci * Cout + co) * 16 + k];
    }
    __syncthreads();

    const int p  = (base % hw) + t * 4;
    const int ow = p % Wout;              // multiple of 4
    const int oh = p / Wout;
    const int x0  = ow >> 1;              // even
    const int ihA = (oh + 1) >> 1;
    const int khA = (oh + 1) & 1;

    float b = bias ? bias[co] : 0.f;
    float a0 = b, a1 = b, a2 = b, a3 = b;
    const int hwin = Hin * Win;
    const float* ip = in + (long long)n * CIN * hwin;

    #pragma unroll 2
    for (int ci = 0; ci < CIN; ++ci) {
        const float* pl = ip + ci * hwin;
        const float* wc = sW + ci * 16;
        #pragma unroll
        for (int a = 0; a < 2; ++a) {
            int ih = ihA - a;
            if ((unsigned)ih < (unsigned)Hin) {
                int kh = khA + 2 * a;
                const float* r = pl + ih * Win;
                float lf = x0 > 0       ? r[x0 - 1] : 0.f;
                float2 m = *reinterpret_cast<const float2*>(r + x0);
                float rt = x0 + 2 < Win ? r[x0 + 2] : 0.f;
                if (RELU_IN) {
                    lf = fmaxf(lf, 0.f); rt = fmaxf(rt, 0.f);
                    m.x = fmaxf(m.x, 0.f); m.y = fmaxf(m.y, 0.f);
                }
                float w0 = wc[kh*4], w1 = wc[kh*4+1], w2 = wc[kh*4+2], w3 = wc[kh*4+3];
                a0 = fmaf(w1, m.x, fmaf(w3, lf,  a0));
                a1 = fmaf(w0, m.y, fmaf(w2, m.x, a1));
                a2 = fmaf(w1, m.y, fmaf(w3, m.x, a2));
                a3 = fmaf(w0, rt,  fmaf(w2, m.y, a3));
            }
        }
    }
    if (RELU_OUT) {
        a0 = fmaxf(a0, 0.f); a1 = fmaxf(a1, 0.f);
        a2 = fmaxf(a2, 0.f); a3 = fmaxf(a3, 0.f);
    }
    *reinterpret_cast<float4*>(out + base + t * 4) = make_float4(a0, a1, a2, a3);
}

// ---------------------------------------------------------------------------
// VQ: unchanged from round 1 (passed; not the bottleneck).
// ---------------------------------------------------------------------------
__global__ __launch_bounds__(256)
void vq_kernel(const float* __restrict__ z, const float* __restrict__ E,
               float* __restrict__ zq, float* __restrict__ stats) {
    __shared__ float sE[128 * 64];
    __shared__ float sN[128];
    __shared__ unsigned shist[512];
    __shared__ float red[256];
    const int t = threadIdx.x;
    for (int i = t; i < 512; i += 256) shist[i] = 0;

    int p0 = blockIdx.x * 512 + t;
    int p1 = p0 + 256;
    int n0 = p0 >> 12, r0 = p0 & 4095;
    int n1 = p1 >> 12, r1 = p1 & 4095;

    float za[64], zb[64];
    #pragma unroll
    for (int d = 0; d < 64; ++d) {
        za[d] = z[(n0 * 64 + d) * 4096 + r0];
        zb[d] = z[(n1 * 64 + d) * 4096 + r1];
    }

    float best0 = 3.4e38f, best1 = 3.4e38f;
    int bi0 = 0, bi1 = 0;

    for (int k0 = 0; k0 < 512; k0 += 128) {
        __syncthreads();
        for (int i = t; i < 128 * 64; i += 256) sE[i] = E[k0 * 64 + i];
        __syncthreads();
        if (t < 128) {
            const float* e = sE + t * 64;
            float s = 0.f;
            #pragma unroll
            for (int d = 0; d < 64; ++d) { float x = e[(d + t) & 63]; s = fmaf(x, x, s); }
            sN[t] = s;
        }
        __syncthreads();
        for (int k = 0; k < 128; ++k) {
            const float4* e4 = reinterpret_cast<const float4*>(sE + (k << 6));
            float s0a = 0.f, s0b = 0.f, s1a = 0.f, s1b = 0.f;
            #pragma unroll
            for (int q = 0; q < 8; ++q) {
                float4 ea = e4[2 * q], eb = e4[2 * q + 1];
                s0a = fmaf(za[8*q+0], ea.x, s0a); s0a = fmaf(za[8*q+1], ea.y, s0a);
                s0a = fmaf(za[8*q+2], ea.z, s0a); s0a = fmaf(za[8*q+3], ea.w, s0a);
                s0b = fmaf(za[8*q+4], eb.x, s0b); s0b = fmaf(za[8*q+5], eb.y, s0b);
                s0b = fmaf(za[8*q+6], eb.z, s0b); s0b = fmaf(za[8*q+7], eb.w, s0b);
                s1a = fmaf(zb[8*q+0], ea.x, s1a); s1a = fmaf(zb[8*q+1], ea.y, s1a);
                s1a = fmaf(zb[8*q+2], ea.z, s1a); s1a = fmaf(zb[8*q+3], ea.w, s1a);
                s1b = fmaf(zb[8*q+4], eb.x, s1b); s1b = fmaf(zb[8*q+5], eb.y, s1b);
                s1b = fmaf(zb[8*q+6], eb.z, s1b); s1b = fmaf(zb[8*q+7], eb.w, s1b);
            }
            float sc0 = sN[k] - 2.f * (s0a + s0b);
            float sc1 = sN[k] - 2.f * (s1a + s1b);
            if (sc0 < best0) { best0 = sc0; bi0 = k0 + k; }
            if (sc1 < best1) { best1 = sc1; bi1 = k0 + k; }
        }
    }

    const float* e0g = E + bi0 * 64;
    const float* e1g = E + bi1 * 64;
    float dist = 0.f;
    #pragma unroll
    for (int d = 0; d < 64; ++d) {
        float ed = e0g[d];
        float df = ed - za[d];
        dist = fmaf(df, df, dist);
        zq[(n0 * 64 + d) * 4096 + r0] = ed;
    }
    #pragma unroll
    for (int d = 0; d < 64; ++d) {
        float ed = e1g[d];
        float df = ed - zb[d];
        dist = fmaf(df, df, dist);
        zq[(n1 * 64 + d) * 4096 + r1] = ed;
    }
    atomicAdd(&shist[bi0], 1u);
    atomicAdd(&shist[bi1], 1u);

    red[t] = dist;
    __syncthreads();
    for (int s = 128; s > 0; s >>= 1) {
        if (t < s) red[t] += red[t + s];
        __syncthreads();
    }
    if (t == 0) atomicAdd(&stats[0], red[0]);
    for (int i = t; i < 512; i += 256) {
        unsigned c = shist[i];
        if (c) atomicAdd(&stats[1 + i], (float)c);
    }
}

__global__ __launch_bounds__(512)
void finalize_kernel(const float* __restrict__ stats, float* __restrict__ out, int plast) {
    __shared__ float red[512];
    int t = threadIdx.x;
    float c = stats[1 + t];
    float p = c * (1.f / 131072.f);
    red[t] = p * logf(p + 1e-10f);
    __syncthreads();
    for (int s = 256; s > 0; s >>= 1) {
        if (t < s) red[t] += red[t + s];
        __syncthreads();
    }
    if (t == 0) {
        out[plast] = expf(-red[0]);
        out[0] = 7.6f * stats[0] * (1.f / 8388608.f);
    }
}

// ---------------------------------------------------------------------------
extern "C" void kernel_launch(void* const* d_in, const int* in_sizes, int n_in,
                              void* d_out, int out_size, void* d_ws, size_t ws_size,
                              hipStream_t stream) {
    (void)in_sizes; (void)n_in; (void)ws_size;
    const float* x   = (const float*)d_in[0];
    const float* w1  = (const float*)d_in[1];
    const float* b1  = (const float*)d_in[2];
    const float* w2  = (const float*)d_in[3];
    const float* b2  = (const float*)d_in[4];
    const float* w3  = (const float*)d_in[5];
    const float* b3  = (const float*)d_in[6];
    const float* r0a = (const float*)d_in[7];
    const float* r0b = (const float*)d_in[8];
    const float* r1a = (const float*)d_in[9];
    const float* r1b = (const float*)d_in[10];
    const float* wp  = (const float*)d_in[11];
    const float* bp  = (const float*)d_in[12];
    const float* E   = (const float*)d_in[13];
    const float* dw1 = (const float*)d_in[14];
    const float* db1 = (const float*)d_in[15];
    const float* dr0a= (const float*)d_in[16];
    const float* dr0b= (const float*)d_in[17];
    const float* dr1a= (const float*)d_in[18];
    const float* dr1b= (const float*)d_in[19];
    const float* tw1 = (const float*)d_in[20];
    const float* tb1 = (const float*)d_in[21];
    const float* tw2 = (const float*)d_in[22];
    const float* tb2 = (const float*)d_in[23];

    float* out = (float*)d_out;
    float* ws  = (float*)d_ws;

    // workspace (floats): P 16.78M | Q 33.55M | ST 513  (~192 MiB total)
    float* P  = ws;
    float* Q  = ws + 16777216;
    float* ST = ws + 50331648;
    float* F  = Q + 16777216;    // encoder res temp
    float* Z  = P;               // pre-VQ output
    float* ZQ = Q + 16777216;    // quantized
    float* F2 = Q;               // decoder res temp

    hipMemsetAsync(ST, 0, 513 * sizeof(float), stream);

    dim3 blk(256);
    // ---- encoder ----
    conv4x4s2_v2<3,  true ><<<65536, blk, 0, stream>>>(x, w1, b1, Q, 64, 256, 256, 128, 128);
    conv4x4s2_v2<64, true ><<<32768, blk, 0, stream>>>(Q, w2, b2, P, 128, 128, 128, 64, 64);
    conv3x3_v4<128,false,false,false><<<16384, blk, 0, stream>>>(P, w3, b3, nullptr, Q, 128, 64, 64);
    // res block 0
    conv3x3_v4<128,true,false,false><<<4096,  blk, 0, stream>>>(Q, r0a, nullptr, nullptr, F, 32, 64, 64);
    conv3x3_v4<32, true,false,true ><<<16384, blk, 0, stream>>>(F, r0b, nullptr, Q, Q, 128, 64, 64);
    // res block 1
    conv3x3_v4<128,true,false,false><<<4096,  blk, 0, stream>>>(Q, r1a, nullptr, nullptr, F, 32, 64, 64);
    conv3x3_v4<32, true,false,true ><<<16384, blk, 0, stream>>>(F, r1b, nullptr, Q, Q, 128, 64, 64);
    // pre-VQ 1x1 (fuses the res-stack's trailing relu)
    conv1x1_v4<128,true><<<8192, blk, 0, stream>>>(Q, wp, bp, Z, 64, 4096);

    // ---- VQ ----
    vq_kernel<<<256, blk, 0, stream>>>(Z, E, ZQ, ST);

    // ---- decoder ----
    conv3x3_v4<64, false,false,false><<<16384, blk, 0, stream>>>(ZQ, dw1, db1, nullptr, P, 128, 64, 64);
    conv3x3_v4<128,true,false,false><<<4096,  blk, 0, stream>>>(P, dr0a, nullptr, nullptr, F2, 32, 64, 64);
    conv3x3_v4<32, true,false,true ><<<16384, blk, 0, stream>>>(F2, dr0b, nullptr, P, P, 128, 64, 64);
    conv3x3_v4<128,true,false,false><<<4096,  blk, 0, stream>>>(P, dr1a, nullptr, nullptr, F2, 32, 64, 64);
    conv3x3_v4<32, true,false,true ><<<16384, blk, 0, stream>>>(F2, dr1b, nullptr, P, P, 128, 64, 64);
    // convT1 (consumes trailing relu via RELU_IN), relu out
    convt_v4<128,true,true ><<<32768, blk, 0, stream>>>(P, tw1, tb1, Q, 64, 64, 64);
    // convT2 -> x_tilda at out[1..]
    convt_v4<64, false,false><<<6144,  blk, 0, stream>>>(Q, tw2, tb2, out + 1, 3, 128, 128);

    // ---- loss / perplexity ----
    finalize_kernel<<<1, 512, 0, stream>>>(ST, out, out_size - 1);
}

// Round 5
// 1375.916 us; speedup vs baseline: 24.5988x; 15.1620x over previous
//
#include <hip/hip_runtime.h>
#include <math.h>

typedef __attribute__((ext_vector_type(8))) short bf16x8;
typedef __attribute__((ext_vector_type(4))) float f32x4;

__device__ inline float bf2f(ushort u) {
    union { uint i; float f; } v; v.i = ((uint)u) << 16; return v.f;
}
__device__ inline ushort f2bf(float f) {
    union { float f; uint i; } v; v.f = f;
    uint b = v.i;
    b += 0x7FFFu + ((b >> 16) & 1u);      // RNE
    return (ushort)(b >> 16);
}
// relu on 2 packed bf16 (zero any half with sign bit set)
__device__ inline uint relu2bf(uint x) {
    uint s = x & 0x80008000u;
    uint m = (s >> 15) * 0xFFFFu;
    return x & ~m;
}

// ---------------------------------------------------------------------------
// Weight transforms -> bf16 [co][tap*CIN+ci]
// ---------------------------------------------------------------------------
template<int CIN, int COUT, int NT>
__global__ __launch_bounds__(256) void wt_oihw(const float* __restrict__ s, ushort* __restrict__ d) {
    int i = blockIdx.x * 256 + threadIdx.x;
    if (i >= COUT * NT * CIN) return;
    int co = i / (NT * CIN);
    int r  = i % (NT * CIN);
    int tap = r / CIN, ci = r % CIN;
    d[i] = f2bf(s[(co * CIN + ci) * NT + tap]);
}

// convT1 tw1 [128ci][64co][4][4] -> 4 classes [cls][64co][4tap*128ci]
__global__ __launch_bounds__(256) void wt_tconv1(const float* __restrict__ s, ushort* __restrict__ d) {
    int i = blockIdx.x * 256 + threadIdx.x;
    if (i >= 4 * 64 * 512) return;
    int cls = i >> 15;
    int co  = (i >> 9) & 63;
    int k   = i & 511;
    int tap = k >> 7, ci = k & 127;
    int a = tap >> 1, b = tap & 1;
    int ph = cls >> 1, pw = cls & 1;
    int kh = ph ? (a ? 2 : 0) : (a ? 3 : 1);
    int kw = pw ? (b ? 2 : 0) : (b ? 3 : 1);
    d[i] = f2bf(s[((ci * 64 + co) << 4) + kh * 4 + kw]);
}

// ---------------------------------------------------------------------------
// MFMA implicit-GEMM conv. NHWC bf16 in/out. Out tile = 64 pixels (one row of
// a 64-wide output grid) x COUT. grid.x = 32 images * 64 rows = 2048.
// CFG0: 3x3 pad1 (S=1); CFG1: 4x4 s2 pad1; CFG2: convT parity class CLS;
// CFG3: 1x1. Weights wt: bf16 [COUT][NT*CIN], K ordered tap-major ci-minor.
// ---------------------------------------------------------------------------
template<int CIN, int COUT, int S, int CFG, int CLS, int NT,
         bool RELU_A, bool RELU_OUT, bool HAS_RES>
__global__ __launch_bounds__(256)
void conv_mfma(const ushort* __restrict__ in, const ushort* __restrict__ wt,
               const float* __restrict__ bias, const ushort* __restrict__ res,
               ushort* __restrict__ out, int Hin, int Win) {
    constexpr int K = NT * CIN;
    constexpr int KSTEPS = K / 32;
    constexpr int CSTEPS = CIN / 32;
    constexpr int WM = (COUT == 128) ? 4 : (COUT == 64) ? 2 : 1;

    __shared__ ushort sA[64 * 40];          // 64 pixels x 32 k, stride 40 (bank-spread)

    const int t = threadIdx.x;
    const int w = t >> 6, l = t & 63;
    const int bid = blockIdx.x;
    const int n = bid >> 6, orow = bid & 63;

    const int m0 = (COUT == 128) ? 0 : (COUT == 64) ? 32 * (w >> 1) : 16 * w;
    const int n0 = (COUT == 128) ? 32 * w : (COUT == 64) ? 32 * (w & 1) : 0;

    f32x4 acc[WM][2] = {};

    const int gm = t >> 2;                  // gather pixel (0..63)
    const int gc = (t & 3) * 8;             // ci offset within 32-chunk

    for (int ks = 0; ks < KSTEPS; ++ks) {
        const int tap = ks / CSTEPS, ci0 = (ks % CSTEPS) * 32;
        int dh, dw;
        if (CFG == 0)      { dh = tap / 3 - 1; dw = tap % 3 - 1; }
        else if (CFG == 1) { dh = tap / 4 - 1; dw = tap % 4 - 1; }
        else if (CFG == 2) { int a = tap >> 1, b = tap & 1;
                             dh = (CLS >> 1) ? 1 - a : -a;
                             dw = (CLS & 1) ? 1 - b : -b; }
        else               { dh = 0; dw = 0; }

        const int ih = S * orow + dh, iw = S * gm + dw;
        uint4 gv = {0u, 0u, 0u, 0u};
        if ((unsigned)ih < (unsigned)Hin && (unsigned)iw < (unsigned)Win) {
            gv = *reinterpret_cast<const uint4*>(
                in + (((long long)(n * Hin + ih)) * Win + iw) * CIN + ci0 + gc);
        }
        if (RELU_A) {
            gv.x = relu2bf(gv.x); gv.y = relu2bf(gv.y);
            gv.z = relu2bf(gv.z); gv.w = relu2bf(gv.w);
        }

        // B fragments straight from L2 (weights shared by all blocks)
        bf16x8 bfr[2];
        #pragma unroll
        for (int nf = 0; nf < 2; ++nf)
            bfr[nf] = *reinterpret_cast<const bf16x8*>(
                wt + (n0 + nf * 16 + (l & 15)) * K + ks * 32 + ((l >> 4) * 8));

        __syncthreads();
        *reinterpret_cast<uint4*>(&sA[gm * 40 + gc]) = gv;
        __syncthreads();

        #pragma unroll
        for (int mf = 0; mf < WM; ++mf) {
            bf16x8 afr = *reinterpret_cast<const bf16x8*>(
                &sA[(m0 + mf * 16 + (l & 15)) * 40 + ((l >> 4) * 8)]);
            #pragma unroll
            for (int nf = 0; nf < 2; ++nf)
                acc[mf][nf] = __builtin_amdgcn_mfma_f32_16x16x32_bf16(
                    afr, bfr[nf], acc[mf][nf], 0, 0, 0);
        }
    }

    // epilogue: C/D layout col=lane&15, row=(lane>>4)*4+r
    #pragma unroll
    for (int mf = 0; mf < WM; ++mf) {
        #pragma unroll
        for (int nf = 0; nf < 2; ++nf) {
            const int col = n0 + nf * 16 + (l & 15);
            const float bv = bias ? bias[col] : 0.f;
            #pragma unroll
            for (int r = 0; r < 4; ++r) {
                const int row = m0 + mf * 16 + ((l >> 4) * 4) + r;
                long long oidx;
                if (CFG == 2)
                    oidx = (((long long)(n * 128 + 2 * orow + (CLS >> 1))) * 128
                            + 2 * row + (CLS & 1)) * COUT + col;
                else
                    oidx = ((long long)bid * 64 + row) * COUT + col;
                float v = acc[mf][nf][r] + bv;
                if (HAS_RES) v += bf2f(res[oidx]);
                if (RELU_OUT) v = fmaxf(v, 0.f);
                out[oidx] = f2bf(v);
            }
        }
    }
}

// ---------------------------------------------------------------------------
// conv1: 3->64, 4x4 s2 pad1, fp32 NCHW in -> bf16 NHWC out, relu.
// grid (32*128, 8): block = (n, oh) row, 16-ow chunk. thread = (co, ow-quad).
// ---------------------------------------------------------------------------
__global__ __launch_bounds__(256)
void conv1_k(const float* __restrict__ x, const float* __restrict__ w1,
             const float* __restrict__ b1, ushort* __restrict__ out) {
    __shared__ float sIn[3 * 4 * 36];
    __shared__ float sW[64 * 48];
    const int t = threadIdx.x;
    const int bid = blockIdx.x;
    const int n = bid >> 7, oh = bid & 127;
    const int ow0 = blockIdx.y * 16;

    for (int i = t; i < 3072; i += 256) sW[i] = w1[i];
    for (int i = t; i < 3 * 4 * 34; i += 256) {
        int ci = i / 136, r = i - ci * 136;
        int r4 = r / 34, iwl = r % 34;
        int ih = 2 * oh - 1 + r4;
        int iw = 2 * ow0 - 1 + iwl;
        float v = 0.f;
        if ((unsigned)ih < 256u && (unsigned)iw < 256u)
            v = x[((n * 3 + ci) * 256 + ih) * 256 + iw];
        sIn[ci * 144 + r4 * 36 + iwl] = v;
    }
    __syncthreads();

    const int co = t & 63, j = t >> 6;
    float wr[48];
    #pragma unroll
    for (int i = 0; i < 48; ++i) wr[i] = sW[co * 48 + i];
    const float bv = b1[co];

    #pragma unroll
    for (int q = 0; q < 4; ++q) {
        const int owl = j * 4 + q;
        float acc = bv;
        #pragma unroll
        for (int ci = 0; ci < 3; ++ci)
            #pragma unroll
            for (int kh = 0; kh < 4; ++kh)
                #pragma unroll
                for (int kw = 0; kw < 4; ++kw)
                    acc = fmaf(sIn[ci * 144 + kh * 36 + 2 * owl + kw],
                               wr[ci * 16 + kh * 4 + kw], acc);
        acc = fmaxf(acc, 0.f);
        out[(((long long)(n * 128 + oh)) * 128 + ow0 + owl) * 64 + co] = f2bf(acc);
    }
}

// ---------------------------------------------------------------------------
// convT2: 64->3, k4 s2 p1, bf16 NHWC in [32,128,128,64] -> fp32 NCHW out.
// grid 32*256, block 256 = one output row.
// ---------------------------------------------------------------------------
__global__ __launch_bounds__(256)
void convt2_k(const ushort* __restrict__ in, const float* __restrict__ tw2,
              const float* __restrict__ tb2, float* __restrict__ out) {
    __shared__ float sW[64 * 48];           // [ci][co][16]
    const int t = threadIdx.x;
    for (int i = t; i < 3072; i += 256) sW[i] = tw2[i];
    __syncthreads();

    const int bid = blockIdx.x;
    const int n = bid >> 8, oh = bid & 255;
    const int ow = t;
    const int khA = (oh + 1) & 1, ihA = (oh + 1) >> 1;
    const int kwA = (ow + 1) & 1, iwA = (ow + 1) >> 1;

    float a0 = tb2[0], a1 = tb2[1], a2 = tb2[2];
    #pragma unroll
    for (int a = 0; a < 2; ++a) {
        const int ih = ihA - a;
        if ((unsigned)ih >= 128u) continue;
        const int kh = khA + 2 * a;
        #pragma unroll
        for (int b = 0; b < 2; ++b) {
            const int iw = iwA - b;
            if ((unsigned)iw >= 128u) continue;
            const int kw = kwA + 2 * b;
            const ushort* src = in + (((long long)(n * 128 + ih)) * 128 + iw) * 64;
            const int k = kh * 4 + kw;
            #pragma unroll
            for (int c8 = 0; c8 < 8; ++c8) {
                uint4 v = *reinterpret_cast<const uint4*>(src + c8 * 8);
                const uint u[4] = {v.x, v.y, v.z, v.w};
                #pragma unroll
                for (int p = 0; p < 4; ++p) {
                    union { uint i; float f; } lo, hi;
                    lo.i = u[p] << 16; hi.i = u[p] & 0xFFFF0000u;
                    const int ci = c8 * 8 + p * 2;
                    a0 = fmaf(lo.f, sW[ci * 48 + 0 * 16 + k], a0);
                    a1 = fmaf(lo.f, sW[ci * 48 + 1 * 16 + k], a1);
                    a2 = fmaf(lo.f, sW[ci * 48 + 2 * 16 + k], a2);
                    a0 = fmaf(hi.f, sW[(ci + 1) * 48 + 0 * 16 + k], a0);
                    a1 = fmaf(hi.f, sW[(ci + 1) * 48 + 1 * 16 + k], a1);
                    a2 = fmaf(hi.f, sW[(ci + 1) * 48 + 2 * 16 + k], a2);
                }
            }
        }
    }
    const long long px = (long long)oh * 256 + ow;
    out[(long long)(n * 3 + 0) * 65536 + px] = a0;
    out[(long long)(n * 3 + 1) * 65536 + px] = a1;
    out[(long long)(n * 3 + 2) * 65536 + px] = a2;
}

// ---------------------------------------------------------------------------
// VQ on NHWC bf16 z [131072 px][64]. 2 px/thread, E fp32 staged 128 at a time.
// ---------------------------------------------------------------------------
__global__ __launch_bounds__(256)
void vq_kernel(const ushort* __restrict__ z, const float* __restrict__ E,
               ushort* __restrict__ zq, float* __restrict__ stats) {
    __shared__ float sE[128 * 64];
    __shared__ float sN[128];
    __shared__ unsigned shist[512];
    __shared__ float red[256];
    const int t = threadIdx.x;
    for (int i = t; i < 512; i += 256) shist[i] = 0;

    const int p0 = blockIdx.x * 512 + t;
    const int p1 = p0 + 256;

    float za[64], zb[64];
    #pragma unroll
    for (int c8 = 0; c8 < 8; ++c8) {
        uint4 va = *reinterpret_cast<const uint4*>(z + (long long)p0 * 64 + c8 * 8);
        uint4 vb = *reinterpret_cast<const uint4*>(z + (long long)p1 * 64 + c8 * 8);
        const uint ua[4] = {va.x, va.y, va.z, va.w};
        const uint ub[4] = {vb.x, vb.y, vb.z, vb.w};
        #pragma unroll
        for (int p = 0; p < 4; ++p) {
            union { uint i; float f; } l0, h0, l1, h1;
            l0.i = ua[p] << 16; h0.i = ua[p] & 0xFFFF0000u;
            l1.i = ub[p] << 16; h1.i = ub[p] & 0xFFFF0000u;
            za[c8 * 8 + p * 2] = l0.f; za[c8 * 8 + p * 2 + 1] = h0.f;
            zb[c8 * 8 + p * 2] = l1.f; zb[c8 * 8 + p * 2 + 1] = h1.f;
        }
    }

    float best0 = 3.4e38f, best1 = 3.4e38f;
    int bi0 = 0, bi1 = 0;

    for (int k0 = 0; k0 < 512; k0 += 128) {
        __syncthreads();
        for (int i = t; i < 128 * 64; i += 256) sE[i] = E[k0 * 64 + i];
        __syncthreads();
        if (t < 128) {
            const float* e = sE + t * 64;
            float s = 0.f;
            #pragma unroll
            for (int d = 0; d < 64; ++d) { float xx = e[(d + t) & 63]; s = fmaf(xx, xx, s); }
            sN[t] = s;
        }
        __syncthreads();
        for (int k = 0; k < 128; ++k) {
            const float4* e4 = reinterpret_cast<const float4*>(sE + (k << 6));
            float s0a = 0.f, s0b = 0.f, s1a = 0.f, s1b = 0.f;
            #pragma unroll
            for (int q = 0; q < 8; ++q) {
                float4 ea = e4[2 * q], eb = e4[2 * q + 1];
                s0a = fmaf(za[8*q+0], ea.x, s0a); s0a = fmaf(za[8*q+1], ea.y, s0a);
                s0a = fmaf(za[8*q+2], ea.z, s0a); s0a = fmaf(za[8*q+3], ea.w, s0a);
                s0b = fmaf(za[8*q+4], eb.x, s0b); s0b = fmaf(za[8*q+5], eb.y, s0b);
                s0b = fmaf(za[8*q+6], eb.z, s0b); s0b = fmaf(za[8*q+7], eb.w, s0b);
                s1a = fmaf(zb[8*q+0], ea.x, s1a); s1a = fmaf(zb[8*q+1], ea.y, s1a);
                s1a = fmaf(zb[8*q+2], ea.z, s1a); s1a = fmaf(zb[8*q+3], ea.w, s1a);
                s1b = fmaf(zb[8*q+4], eb.x, s1b); s1b = fmaf(zb[8*q+5], eb.y, s1b);
                s1b = fmaf(zb[8*q+6], eb.z, s1b); s1b = fmaf(zb[8*q+7], eb.w, s1b);
            }
            float sc0 = sN[k] - 2.f * (s0a + s0b);
            float sc1 = sN[k] - 2.f * (s1a + s1b);
            if (sc0 < best0) { best0 = sc0; bi0 = k0 + k; }
            if (sc1 < best1) { best1 = sc1; bi1 = k0 + k; }
        }
    }

    const float* e0g = E + bi0 * 64;
    const float* e1g = E + bi1 * 64;
    float dist = 0.f;
    ushort pk[8];
    #pragma unroll
    for (int c8 = 0; c8 < 8; ++c8) {
        #pragma unroll
        for (int p = 0; p < 8; ++p) {
            const float ed = e0g[c8 * 8 + p];
            const float df = ed - za[c8 * 8 + p];
            dist = fmaf(df, df, dist);
            pk[p] = f2bf(ed);
        }
        *reinterpret_cast<uint4*>(zq + (long long)p0 * 64 + c8 * 8) =
            *reinterpret_cast<const uint4*>(pk);
    }
    #pragma unroll
    for (int c8 = 0; c8 < 8; ++c8) {
        #pragma unroll
        for (int p = 0; p < 8; ++p) {
            const float ed = e1g[c8 * 8 + p];
            const float df = ed - zb[c8 * 8 + p];
            dist = fmaf(df, df, dist);
            pk[p] = f2bf(ed);
        }
        *reinterpret_cast<uint4*>(zq + (long long)p1 * 64 + c8 * 8) =
            *reinterpret_cast<const uint4*>(pk);
    }
    atomicAdd(&shist[bi0], 1u);
    atomicAdd(&shist[bi1], 1u);

    red[t] = dist;
    __syncthreads();
    for (int s = 128; s > 0; s >>= 1) {
        if (t < s) red[t] += red[t + s];
        __syncthreads();
    }
    if (t == 0) atomicAdd(&stats[0], red[0]);
    for (int i = t; i < 512; i += 256) {
        unsigned c = shist[i];
        if (c) atomicAdd(&stats[1 + i], (float)c);
    }
}

__global__ __launch_bounds__(512)
void finalize_kernel(const float* __restrict__ stats, float* __restrict__ out, int plast) {
    __shared__ float red[512];
    int t = threadIdx.x;
    float c = stats[1 + t];
    float p = c * (1.f / 131072.f);
    red[t] = p * logf(p + 1e-10f);
    __syncthreads();
    for (int s = 256; s > 0; s >>= 1) {
        if (t < s) red[t] += red[t + s];
        __syncthreads();
    }
    if (t == 0) {
        out[plast] = expf(-red[0]);
        out[0] = 7.6f * stats[0] * (1.f / 8388608.f);
    }
}

// ---------------------------------------------------------------------------
extern "C" void kernel_launch(void* const* d_in, const int* in_sizes, int n_in,
                              void* d_out, int out_size, void* d_ws, size_t ws_size,
                              hipStream_t stream) {
    (void)in_sizes; (void)n_in; (void)ws_size;
    const float* x   = (const float*)d_in[0];
    const float* w1  = (const float*)d_in[1];
    const float* b1  = (const float*)d_in[2];
    const float* w2  = (const float*)d_in[3];
    const float* b2  = (const float*)d_in[4];
    const float* w3  = (const float*)d_in[5];
    const float* b3  = (const float*)d_in[6];
    const float* r0a = (const float*)d_in[7];
    const float* r0b = (const float*)d_in[8];
    const float* r1a = (const float*)d_in[9];
    const float* r1b = (const float*)d_in[10];
    const float* wp  = (const float*)d_in[11];
    const float* bp  = (const float*)d_in[12];
    const float* E   = (const float*)d_in[13];
    const float* dw1 = (const float*)d_in[14];
    const float* db1 = (const float*)d_in[15];
    const float* dr0a= (const float*)d_in[16];
    const float* dr0b= (const float*)d_in[17];
    const float* dr1a= (const float*)d_in[18];
    const float* dr1b= (const float*)d_in[19];
    const float* tw1 = (const float*)d_in[20];
    const float* tb1 = (const float*)d_in[21];
    const float* tw2 = (const float*)d_in[22];
    const float* tb2 = (const float*)d_in[23];

    float* out = (float*)d_out;
    ushort* ws = (ushort*)d_ws;

    // bf16 activation buffers (NHWC), ~178 MB total
    ushort* H1 = ws;                  // [32,128,128,64] 33,554,432 ; later convT1 out T
    ushort* H2 = ws + 33554432;       // [32,64,64,128] 16,777,216  ; later decoder D
    ushort* C  = ws + 50331648;       // [32,64,64,128] 16,777,216
    ushort* F  = ws + 67108864;       // [32,64,64,32]   4,194,304 (res temp)
    ushort* Z  = ws + 71303168;       // [131072,64]     8,388,608
    ushort* ZQ = ws + 79691776;       // [131072,64]     8,388,608
    ushort* W0 = ws + 88080384;       // weight block
    ushort* Wt2   = W0;               // 131072
    ushort* Wt3   = W0 + 131072;      // 147456
    ushort* Wr0a  = W0 + 278528;      // 36864
    ushort* Wr0b  = W0 + 315392;
    ushort* Wr1a  = W0 + 352256;
    ushort* Wr1b  = W0 + 389120;
    ushort* Wp    = W0 + 425984;      // 8192
    ushort* Wd1   = W0 + 434176;      // 73728
    ushort* Wdr0a = W0 + 507904;
    ushort* Wdr0b = W0 + 544768;
    ushort* Wdr1a = W0 + 581632;
    ushort* Wdr1b = W0 + 618496;
    ushort* WT1   = W0 + 655360;      // 131072
    float*  ST    = (float*)(ws + 88866816);
    ushort* T = H1;
    ushort* D = H2;

    hipMemsetAsync(ST, 0, 513 * sizeof(float), stream);

    dim3 blk(256);
    // weight transforms (bf16, k = tap*CIN+ci)
    wt_oihw<64, 128,16><<<512, blk, 0, stream>>>(w2,  Wt2);
    wt_oihw<128,128, 9><<<576, blk, 0, stream>>>(w3,  Wt3);
    wt_oihw<128, 32, 9><<<144, blk, 0, stream>>>(r0a, Wr0a);
    wt_oihw<32, 128, 9><<<144, blk, 0, stream>>>(r0b, Wr0b);
    wt_oihw<128, 32, 9><<<144, blk, 0, stream>>>(r1a, Wr1a);
    wt_oihw<32, 128, 9><<<144, blk, 0, stream>>>(r1b, Wr1b);
    wt_oihw<128, 64, 1><<<32,  blk, 0, stream>>>(wp,  Wp);
    wt_oihw<64, 128, 9><<<288, blk, 0, stream>>>(dw1, Wd1);
    wt_oihw<128, 32, 9><<<144, blk, 0, stream>>>(dr0a, Wdr0a);
    wt_oihw<32, 128, 9><<<144, blk, 0, stream>>>(dr0b, Wdr0b);
    wt_oihw<128, 32, 9><<<144, blk, 0, stream>>>(dr1a, Wdr1a);
    wt_oihw<32, 128, 9><<<144, blk, 0, stream>>>(dr1b, Wdr1b);
    wt_tconv1<<<512, blk, 0, stream>>>(tw1, WT1);

    // ---- encoder ----
    conv1_k<<<dim3(32 * 128, 8), blk, 0, stream>>>(x, w1, b1, H1);
    conv_mfma<64,128,2,1,0,16,false,true ,false><<<2048, blk, 0, stream>>>(H1, Wt2, b2, nullptr, H2, 128, 128);
    conv_mfma<128,128,1,0,0, 9,false,false,false><<<2048, blk, 0, stream>>>(H2, Wt3, b3, nullptr, C, 64, 64);
    // res block 0: F = relu(conv(relu(C))); C += conv(F)
    conv_mfma<128, 32,1,0,0, 9,true ,true ,false><<<2048, blk, 0, stream>>>(C, Wr0a, nullptr, nullptr, F, 64, 64);
    conv_mfma<32, 128,1,0,0, 9,false,false,true ><<<2048, blk, 0, stream>>>(F, Wr0b, nullptr, C, C, 64, 64);
    // res block 1 (trailing relu of the stack fused into r1b)
    conv_mfma<128, 32,1,0,0, 9,true ,true ,false><<<2048, blk, 0, stream>>>(C, Wr1a, nullptr, nullptr, F, 64, 64);
    conv_mfma<32, 128,1,0,0, 9,false,true ,true ><<<2048, blk, 0, stream>>>(F, Wr1b, nullptr, C, C, 64, 64);
    // pre-VQ 1x1
    conv_mfma<128, 64,1,3,0, 1,false,false,false><<<2048, blk, 0, stream>>>(C, Wp, bp, nullptr, Z, 64, 64);

    // ---- VQ ----
    vq_kernel<<<256, blk, 0, stream>>>(Z, E, ZQ, ST);

    // ---- decoder ----
    conv_mfma<64,128,1,0,0, 9,false,false,false><<<2048, blk, 0, stream>>>(ZQ, Wd1, db1, nullptr, D, 64, 64);
    conv_mfma<128, 32,1,0,0, 9,true ,true ,false><<<2048, blk, 0, stream>>>(D, Wdr0a, nullptr, nullptr, F, 64, 64);
    conv_mfma<32, 128,1,0,0, 9,false,false,true ><<<2048, blk, 0, stream>>>(F, Wdr0b, nullptr, D, D, 64, 64);
    conv_mfma<128, 32,1,0,0, 9,true ,true ,false><<<2048, blk, 0, stream>>>(D, Wdr1a, nullptr, nullptr, F, 64, 64);
    conv_mfma<32, 128,1,0,0, 9,false,true ,true ><<<2048, blk, 0, stream>>>(F, Wdr1b, nullptr, D, D, 64, 64);
    // convT1: 4 parity classes, relu out
    conv_mfma<128, 64,1,2,0, 4,false,true ,false><<<2048, blk, 0, stream>>>(D, WT1 + 0 * 32768, tb1, nullptr, T, 64, 64);
    conv_mfma<128, 64,1,2,1, 4,false,true ,false><<<2048, blk, 0, stream>>>(D, WT1 + 1 * 32768, tb1, nullptr, T, 64, 64);
    conv_mfma<128, 64,1,2,2, 4,false,true ,false><<<2048, blk, 0, stream>>>(D, WT1 + 2 * 32768, tb1, nullptr, T, 64, 64);
    conv_mfma<128, 64,1,2,3, 4,false,true ,false><<<2048, blk, 0, stream>>>(D, WT1 + 3 * 32768, tb1, nullptr, T, 64, 64);
    // convT2 -> x_tilda (fp32 NCHW) at out[1..]
    convt2_k<<<32 * 256, blk, 0, stream>>>(T, tw2, tb2, out + 1);

    // ---- loss / perplexity ----
    finalize_kernel<<<1, 512, 0, stream>>>(ST, out, out_size - 1);
}

// Round 6
// 1328.115 us; speedup vs baseline: 25.4841x; 1.0360x over previous
//
#include <hip/hip_runtime.h>
#include <math.h>

typedef __attribute__((ext_vector_type(8))) short bf16x8;
typedef __attribute__((ext_vector_type(4))) float f32x4;

__device__ inline float bf2f(ushort u) {
    union { uint i; float f; } v; v.i = ((uint)u) << 16; return v.f;
}
__device__ inline ushort f2bf(float f) {
    union { float f; uint i; } v; v.f = f;
    uint b = v.i;
    b += 0x7FFFu + ((b >> 16) & 1u);      // RNE
    return (ushort)(b >> 16);
}
__device__ inline uint relu2bf(uint x) {
    uint s = x & 0x80008000u;
    uint m = (s >> 15) * 0xFFFFu;
    return x & ~m;
}

// ---------------------------------------------------------------------------
// Weight transforms -> bf16 [co][tap*CIN+ci]
// ---------------------------------------------------------------------------
template<int CIN, int COUT, int NT>
__global__ __launch_bounds__(256) void wt_oihw(const float* __restrict__ s, ushort* __restrict__ d) {
    int i = blockIdx.x * 256 + threadIdx.x;
    if (i >= COUT * NT * CIN) return;
    int co = i / (NT * CIN);
    int r  = i % (NT * CIN);
    int tap = r / CIN, ci = r % CIN;
    d[i] = f2bf(s[(co * CIN + ci) * NT + tap]);
}

// convT1 tw1 [128ci][64co][4][4] -> 4 classes [cls][64co][4tap*128ci]
__global__ __launch_bounds__(256) void wt_tconv1(const float* __restrict__ s, ushort* __restrict__ d) {
    int i = blockIdx.x * 256 + threadIdx.x;
    if (i >= 4 * 64 * 512) return;
    int cls = i >> 15;
    int co  = (i >> 9) & 63;
    int k   = i & 511;
    int tap = k >> 7, ci = k & 127;
    int a = tap >> 1, b = tap & 1;
    int ph = cls >> 1, pw = cls & 1;
    int kh = ph ? (a ? 2 : 0) : (a ? 3 : 1);
    int kw = pw ? (b ? 2 : 0) : (b ? 3 : 1);
    d[i] = f2bf(s[((ci * 64 + co) << 4) + kh * 4 + kw]);
}

// E -> bf16 copy + per-code squared norms
__global__ __launch_bounds__(256) void vq_prep(const float* __restrict__ E,
                                               ushort* __restrict__ Ebf, float* __restrict__ eN) {
    int i = blockIdx.x * 256 + threadIdx.x;
    if (i < 32768) Ebf[i] = f2bf(E[i]);
    if (i < 512) {
        float s = 0.f;
        #pragma unroll 8
        for (int d = 0; d < 64; ++d) { float x = E[i * 64 + d]; s = fmaf(x, x, s); }
        eN[i] = s;
    }
}

// ---------------------------------------------------------------------------
// MFMA implicit-GEMM conv v2. NHWC bf16. 128-px M-tile (2 output rows of a
// 64-wide map), grid = 32 img * 32 row-pairs = 1024. 4 waves, single barrier
// per K-step, register-staged A prefetch, double-buffered LDS A-tile.
// CFG0: 3x3 p1; CFG1: 4x4 s2 p1; CFG2: convT parity CLS; CFG3: 1x1.
// wt: bf16 [COUT][NT*CIN], tap-major ci-minor.
// ---------------------------------------------------------------------------
template<int CIN, int COUT, int S, int CFG, int CLS, int NT,
         bool RELU_A, bool RELU_OUT, bool HAS_RES>
__global__ __launch_bounds__(256)
void conv_mfma2(const ushort* __restrict__ in, const ushort* __restrict__ wt,
                const float* __restrict__ bias, const ushort* __restrict__ res,
                ushort* __restrict__ out, int Hin, int Win) {
    constexpr int K = NT * CIN;
    constexpr int KSTEPS = K / 32;
    constexpr int CSTEPS = CIN / 32;
    constexpr int WM = (COUT == 128) ? 4 : 2;   // 16-px m-frags per wave
    constexpr int WN = (COUT == 32) ? 2 : 4;    // 16-co n-frags per wave

    __shared__ ushort sA[2][128 * 40];

    const int t = threadIdx.x;
    const int w = t >> 6, l = t & 63;
    const int bid = blockIdx.x;
    const int n = bid >> 5, R = bid & 31;       // row-pair index

    const int m0 = (COUT == 128) ? 64 * (w >> 1) : 32 * w;
    const int n0 = (COUT == 128) ? 64 * (w & 1) : 0;

    const int gpx  = t >> 1;                    // staged pixel 0..127
    const int gk   = (t & 1) * 16;              // k-offset within 32-chunk
    const int grow = 2 * R + (gpx >> 6);        // output row
    const int gcol = gpx & 63;                  // output col

    auto gather = [&](int ks, uint4& g0, uint4& g1) {
        int tap, ci0;
        if (CSTEPS == 1) { tap = ks; ci0 = 0; }
        else             { tap = ks / CSTEPS; ci0 = (ks % CSTEPS) * 32; }
        int dh, dw;
        if (CFG == 0)      { dh = tap / 3 - 1; dw = tap % 3 - 1; }
        else if (CFG == 1) { dh = tap / 4 - 1; dw = tap % 4 - 1; }
        else if (CFG == 2) { int a = tap >> 1, b = tap & 1;
                             dh = (CLS >> 1) ? 1 - a : -a;
                             dw = (CLS & 1) ? 1 - b : -b; }
        else               { dh = 0; dw = 0; }
        const int ih = S * grow + dh, iw = S * gcol + dw;
        g0 = make_uint4(0u, 0u, 0u, 0u); g1 = g0;
        if ((unsigned)ih < (unsigned)Hin && (unsigned)iw < (unsigned)Win) {
            const ushort* p = in + (((long long)(n * Hin + ih)) * Win + iw) * CIN + ci0 + gk;
            g0 = *reinterpret_cast<const uint4*>(p);
            g1 = *reinterpret_cast<const uint4*>(p + 8);
        }
        if (RELU_A) {
            g0.x = relu2bf(g0.x); g0.y = relu2bf(g0.y); g0.z = relu2bf(g0.z); g0.w = relu2bf(g0.w);
            g1.x = relu2bf(g1.x); g1.y = relu2bf(g1.y); g1.z = relu2bf(g1.z); g1.w = relu2bf(g1.w);
        }
    };

    f32x4 acc[WM][WN] = {};

    uint4 g0, g1;
    gather(0, g0, g1);
    *reinterpret_cast<uint4*>(&sA[0][gpx * 40 + gk])     = g0;
    *reinterpret_cast<uint4*>(&sA[0][gpx * 40 + gk + 8]) = g1;
    __syncthreads();

    int cur = 0;
    for (int ks = 0; ks < KSTEPS; ++ks) {
        const bool more = (ks + 1 < KSTEPS);
        uint4 h0, h1;
        if (more) gather(ks + 1, h0, h1);

        bf16x8 bfr[WN];
        #pragma unroll
        for (int nf = 0; nf < WN; ++nf)
            bfr[nf] = *reinterpret_cast<const bf16x8*>(
                wt + (n0 + nf * 16 + (l & 15)) * K + ks * 32 + ((l >> 4) * 8));

        bf16x8 afr[WM];
        #pragma unroll
        for (int mf = 0; mf < WM; ++mf)
            afr[mf] = *reinterpret_cast<const bf16x8*>(
                &sA[cur][(m0 + mf * 16 + (l & 15)) * 40 + ((l >> 4) * 8)]);

        #pragma unroll
        for (int mf = 0; mf < WM; ++mf)
            #pragma unroll
            for (int nf = 0; nf < WN; ++nf)
                acc[mf][nf] = __builtin_amdgcn_mfma_f32_16x16x32_bf16(
                    afr[mf], bfr[nf], acc[mf][nf], 0, 0, 0);

        if (more) {
            *reinterpret_cast<uint4*>(&sA[cur ^ 1][gpx * 40 + gk])     = h0;
            *reinterpret_cast<uint4*>(&sA[cur ^ 1][gpx * 40 + gk + 8]) = h1;
            __syncthreads();
            cur ^= 1;
        }
    }

    // epilogue: C/D layout col=lane&15, row=(lane>>4)*4+r
    #pragma unroll
    for (int mf = 0; mf < WM; ++mf) {
        #pragma unroll
        for (int nf = 0; nf < WN; ++nf) {
            const int col = n0 + nf * 16 + (l & 15);
            const float bv = bias ? bias[col] : 0.f;
            #pragma unroll
            for (int r = 0; r < 4; ++r) {
                const int prow = m0 + mf * 16 + ((l >> 4) * 4) + r;   // 0..127
                const int orow = 2 * R + (prow >> 6);
                const int ocol = prow & 63;
                long long oidx;
                if (CFG == 2)
                    oidx = (((long long)(n * 128 + 2 * orow + (CLS >> 1))) * 128
                            + 2 * ocol + (CLS & 1)) * COUT + col;
                else
                    oidx = (((long long)(n * 64 + orow)) * 64 + ocol) * COUT + col;
                float v = acc[mf][nf][r] + bv;
                if (HAS_RES) v += bf2f(res[oidx]);
                if (RELU_OUT) v = fmaxf(v, 0.f);
                out[oidx] = f2bf(v);
            }
        }
    }
}

// ---------------------------------------------------------------------------
// conv1: 3->64, 4x4 s2 pad1, fp32 NCHW in -> bf16 NHWC out, relu.
// ---------------------------------------------------------------------------
__global__ __launch_bounds__(256)
void conv1_k(const float* __restrict__ x, const float* __restrict__ w1,
             const float* __restrict__ b1, ushort* __restrict__ out) {
    __shared__ float sIn[3 * 4 * 36];
    __shared__ float sW[64 * 48];
    const int t = threadIdx.x;
    const int bid = blockIdx.x;
    const int n = bid >> 7, oh = bid & 127;
    const int ow0 = blockIdx.y * 16;

    for (int i = t; i < 3072; i += 256) sW[i] = w1[i];
    for (int i = t; i < 3 * 4 * 34; i += 256) {
        int ci = i / 136, r = i - ci * 136;
        int r4 = r / 34, iwl = r % 34;
        int ih = 2 * oh - 1 + r4;
        int iw = 2 * ow0 - 1 + iwl;
        float v = 0.f;
        if ((unsigned)ih < 256u && (unsigned)iw < 256u)
            v = x[((n * 3 + ci) * 256 + ih) * 256 + iw];
        sIn[ci * 144 + r4 * 36 + iwl] = v;
    }
    __syncthreads();

    const int co = t & 63, j = t >> 6;
    float wr[48];
    #pragma unroll
    for (int i = 0; i < 48; ++i) wr[i] = sW[co * 48 + i];
    const float bv = b1[co];

    #pragma unroll
    for (int q = 0; q < 4; ++q) {
        const int owl = j * 4 + q;
        float acc = bv;
        #pragma unroll
        for (int ci = 0; ci < 3; ++ci)
            #pragma unroll
            for (int kh = 0; kh < 4; ++kh)
                #pragma unroll
                for (int kw = 0; kw < 4; ++kw)
                    acc = fmaf(sIn[ci * 144 + kh * 36 + 2 * owl + kw],
                               wr[ci * 16 + kh * 4 + kw], acc);
        acc = fmaxf(acc, 0.f);
        out[(((long long)(n * 128 + oh)) * 128 + ow0 + owl) * 64 + co] = f2bf(acc);
    }
}

// ---------------------------------------------------------------------------
// convT2: 64->3, k4 s2 p1, bf16 NHWC in [32,128,128,64] -> fp32 NCHW out.
// ---------------------------------------------------------------------------
__global__ __launch_bounds__(256)
void convt2_k(const ushort* __restrict__ in, const float* __restrict__ tw2,
              const float* __restrict__ tb2, float* __restrict__ out) {
    __shared__ float sW[64 * 48];           // [ci][co][16]
    const int t = threadIdx.x;
    for (int i = t; i < 3072; i += 256) sW[i] = tw2[i];
    __syncthreads();

    const int bid = blockIdx.x;
    const int n = bid >> 8, oh = bid & 255;
    const int ow = t;
    const int khA = (oh + 1) & 1, ihA = (oh + 1) >> 1;
    const int kwA = (ow + 1) & 1, iwA = (ow + 1) >> 1;

    float a0 = tb2[0], a1 = tb2[1], a2 = tb2[2];
    #pragma unroll
    for (int a = 0; a < 2; ++a) {
        const int ih = ihA - a;
        if ((unsigned)ih >= 128u) continue;
        const int kh = khA + 2 * a;
        #pragma unroll
        for (int b = 0; b < 2; ++b) {
            const int iw = iwA - b;
            if ((unsigned)iw >= 128u) continue;
            const int kw = kwA + 2 * b;
            const ushort* src = in + (((long long)(n * 128 + ih)) * 128 + iw) * 64;
            const int k = kh * 4 + kw;
            #pragma unroll
            for (int c8 = 0; c8 < 8; ++c8) {
                uint4 v = *reinterpret_cast<const uint4*>(src + c8 * 8);
                const uint u[4] = {v.x, v.y, v.z, v.w};
                #pragma unroll
                for (int p = 0; p < 4; ++p) {
                    union { uint i; float f; } lo, hi;
                    lo.i = u[p] << 16; hi.i = u[p] & 0xFFFF0000u;
                    const int ci = c8 * 8 + p * 2;
                    a0 = fmaf(lo.f, sW[ci * 48 + 0 * 16 + k], a0);
                    a1 = fmaf(lo.f, sW[ci * 48 + 1 * 16 + k], a1);
                    a2 = fmaf(lo.f, sW[ci * 48 + 2 * 16 + k], a2);
                    a0 = fmaf(hi.f, sW[(ci + 1) * 48 + 0 * 16 + k], a0);
                    a1 = fmaf(hi.f, sW[(ci + 1) * 48 + 1 * 16 + k], a1);
                    a2 = fmaf(hi.f, sW[(ci + 1) * 48 + 2 * 16 + k], a2);
                }
            }
        }
    }
    const long long px = (long long)oh * 256 + ow;
    out[(long long)(n * 3 + 0) * 65536 + px] = a0;
    out[(long long)(n * 3 + 1) * 65536 + px] = a1;
    out[(long long)(n * 3 + 2) * 65536 + px] = a2;
}

// ---------------------------------------------------------------------------
// MFMA VQ: scores = ||e||^2 - 2 z.E^T via mfma. Block = 64 px, 4 waves each
// handling a 128-code slice. Argmin: per-lane over 8 nfrags -> 16-lane
// shfl_xor reduce -> cross-wave LDS reduce. grid 2048.
// ---------------------------------------------------------------------------
__global__ __launch_bounds__(256)
void vq_mfma(const ushort* __restrict__ z, const ushort* __restrict__ Ebf,
             const float* __restrict__ E, const float* __restrict__ eN,
             ushort* __restrict__ zq, float* __restrict__ stats) {
    __shared__ ushort sZ[64 * 72];
    __shared__ float sEN[512];
    __shared__ float sV[64 * 4];
    __shared__ int   sI[64 * 4];
    __shared__ int   sIdx[64];
    __shared__ unsigned shist[512];
    __shared__ float red[256];

    const int t = threadIdx.x;
    const int w = t >> 6, l = t & 63;
    const long long p0 = (long long)blockIdx.x * 64;

    // stage z tile (64 px x 64 k), eN, zero hist
    {
        const int px = t >> 2, koff = (t & 3) * 16;
        const ushort* p = z + (p0 + px) * 64 + koff;
        uint4 a0 = *reinterpret_cast<const uint4*>(p);
        uint4 a1 = *reinterpret_cast<const uint4*>(p + 8);
        *reinterpret_cast<uint4*>(&sZ[px * 72 + koff])     = a0;
        *reinterpret_cast<uint4*>(&sZ[px * 72 + koff + 8]) = a1;
        sEN[t] = eN[t]; sEN[t + 256] = eN[t + 256];
        shist[t] = 0u; shist[t + 256] = 0u;
    }
    __syncthreads();

    f32x4 acc[4][8] = {};
    #pragma unroll
    for (int ks = 0; ks < 2; ++ks) {
        bf16x8 bfr[8];
        #pragma unroll
        for (int nf = 0; nf < 8; ++nf)
            bfr[nf] = *reinterpret_cast<const bf16x8*>(
                Ebf + (w * 128 + nf * 16 + (l & 15)) * 64 + ks * 32 + ((l >> 4) * 8));
        #pragma unroll
        for (int mf = 0; mf < 4; ++mf) {
            bf16x8 afr = *reinterpret_cast<const bf16x8*>(
                &sZ[(mf * 16 + (l & 15)) * 72 + ks * 32 + ((l >> 4) * 8)]);
            #pragma unroll
            for (int nf = 0; nf < 8; ++nf)
                acc[mf][nf] = __builtin_amdgcn_mfma_f32_16x16x32_bf16(
                    afr, bfr[nf], acc[mf][nf], 0, 0, 0);
        }
    }

    // scores + argmin
    float eNr[8];
    #pragma unroll
    for (int nf = 0; nf < 8; ++nf) eNr[nf] = sEN[w * 128 + nf * 16 + (l & 15)];

    #pragma unroll
    for (int mf = 0; mf < 4; ++mf) {
        #pragma unroll
        for (int r = 0; r < 4; ++r) {
            float best = 3.4e38f; int bidx = 0;
            #pragma unroll
            for (int nf = 0; nf < 8; ++nf) {
                float s = eNr[nf] - 2.f * acc[mf][nf][r];
                int   c = w * 128 + nf * 16 + (l & 15);
                if (s < best || (s == best && c < bidx)) { best = s; bidx = c; }
            }
            #pragma unroll
            for (int off = 1; off < 16; off <<= 1) {
                float ov = __shfl_xor(best, off);
                int   oi = __shfl_xor(bidx, off);
                if (ov < best || (ov == best && oi < bidx)) { best = ov; bidx = oi; }
            }
            if ((l & 15) == 0) {
                const int px = mf * 16 + ((l >> 4) * 4) + r;
                sV[px * 4 + w] = best; sI[px * 4 + w] = bidx;
            }
        }
    }
    __syncthreads();

    if (t < 64) {
        float best = sV[t * 4]; int bidx = sI[t * 4];
        #pragma unroll
        for (int w2 = 1; w2 < 4; ++w2) {
            float v = sV[t * 4 + w2]; int c = sI[t * 4 + w2];
            if (v < best || (v == best && c < bidx)) { best = v; bidx = c; }
        }
        sIdx[t] = bidx;
        atomicAdd(&shist[bidx], 1u);
    }
    __syncthreads();

    // epilogue: q gather (fp32 E), dist, zq write
    {
        const int px = t >> 2, doff = (t & 3) * 16;
        const int idx = sIdx[px];
        const float* e = E + idx * 64 + doff;
        float dist = 0.f;
        uint4 pk4[2];
        ushort* pk = reinterpret_cast<ushort*>(pk4);
        #pragma unroll
        for (int j = 0; j < 16; ++j) {
            float ev = e[j];
            float zv = bf2f(sZ[px * 72 + doff + j]);
            float df = ev - zv;
            dist = fmaf(df, df, dist);
            pk[j] = f2bf(ev);
        }
        *reinterpret_cast<uint4*>(zq + (p0 + px) * 64 + doff)     = pk4[0];
        *reinterpret_cast<uint4*>(zq + (p0 + px) * 64 + doff + 8) = pk4[1];
        red[t] = dist;
    }
    __syncthreads();
    for (int s = 128; s > 0; s >>= 1) {
        if (t < s) red[t] += red[t + s];
        __syncthreads();
    }
    if (t == 0) atomicAdd(&stats[0], red[0]);
    for (int i = t; i < 512; i += 256) {
        unsigned c = shist[i];
        if (c) atomicAdd(&stats[1 + i], (float)c);
    }
}

__global__ __launch_bounds__(512)
void finalize_kernel(const float* __restrict__ stats, float* __restrict__ out, int plast) {
    __shared__ float red[512];
    int t = threadIdx.x;
    float c = stats[1 + t];
    float p = c * (1.f / 131072.f);
    red[t] = p * logf(p + 1e-10f);
    __syncthreads();
    for (int s = 256; s > 0; s >>= 1) {
        if (t < s) red[t] += red[t + s];
        __syncthreads();
    }
    if (t == 0) {
        out[plast] = expf(-red[0]);
        out[0] = 7.6f * stats[0] * (1.f / 8388608.f);
    }
}

// ---------------------------------------------------------------------------
extern "C" void kernel_launch(void* const* d_in, const int* in_sizes, int n_in,
                              void* d_out, int out_size, void* d_ws, size_t ws_size,
                              hipStream_t stream) {
    (void)in_sizes; (void)n_in; (void)ws_size;
    const float* x   = (const float*)d_in[0];
    const float* w1  = (const float*)d_in[1];
    const float* b1  = (const float*)d_in[2];
    const float* w2  = (const float*)d_in[3];
    const float* b2  = (const float*)d_in[4];
    const float* w3  = (const float*)d_in[5];
    const float* b3  = (const float*)d_in[6];
    const float* r0a = (const float*)d_in[7];
    const float* r0b = (const float*)d_in[8];
    const float* r1a = (const float*)d_in[9];
    const float* r1b = (const float*)d_in[10];
    const float* wp  = (const float*)d_in[11];
    const float* bp  = (const float*)d_in[12];
    const float* E   = (const float*)d_in[13];
    const float* dw1 = (const float*)d_in[14];
    const float* db1 = (const float*)d_in[15];
    const float* dr0a= (const float*)d_in[16];
    const float* dr0b= (const float*)d_in[17];
    const float* dr1a= (const float*)d_in[18];
    const float* dr1b= (const float*)d_in[19];
    const float* tw1 = (const float*)d_in[20];
    const float* tb1 = (const float*)d_in[21];
    const float* tw2 = (const float*)d_in[22];
    const float* tb2 = (const float*)d_in[23];

    float* out = (float*)d_out;
    ushort* ws = (ushort*)d_ws;

    // bf16 activation buffers (NHWC)
    ushort* H1 = ws;                  // [32,128,128,64] ; later convT1 out T
    ushort* H2 = ws + 33554432;       // [32,64,64,128]  ; later decoder D
    ushort* C  = ws + 50331648;       // [32,64,64,128]
    ushort* F  = ws + 67108864;       // [32,64,64,32]  res temp
    ushort* Z  = ws + 71303168;       // [131072,64]
    ushort* ZQ = ws + 79691776;       // [131072,64]
    ushort* W0 = ws + 88080384;       // weight block
    ushort* Wt2   = W0;               // 131072
    ushort* Wt3   = W0 + 131072;      // 147456
    ushort* Wr0a  = W0 + 278528;
    ushort* Wr0b  = W0 + 315392;
    ushort* Wr1a  = W0 + 352256;
    ushort* Wr1b  = W0 + 389120;
    ushort* Wp    = W0 + 425984;
    ushort* Wd1   = W0 + 434176;
    ushort* Wdr0a = W0 + 507904;
    ushort* Wdr0b = W0 + 544768;
    ushort* Wdr1a = W0 + 581632;
    ushort* Wdr1b = W0 + 618496;
    ushort* WT1   = W0 + 655360;      // 131072 -> ends W0+786432
    ushort* Ebf   = W0 + 786432;      // 32768
    float*  eN    = (float*)(W0 + 819200);   // 512 floats
    float*  ST    = (float*)(W0 + 820224);   // 513 floats
    ushort* T = H1;
    ushort* D = H2;

    hipMemsetAsync(ST, 0, 513 * sizeof(float), stream);

    dim3 blk(256);
    // weight transforms
    wt_oihw<64, 128,16><<<512, blk, 0, stream>>>(w2,  Wt2);
    wt_oihw<128,128, 9><<<576, blk, 0, stream>>>(w3,  Wt3);
    wt_oihw<128, 32, 9><<<144, blk, 0, stream>>>(r0a, Wr0a);
    wt_oihw<32, 128, 9><<<144, blk, 0, stream>>>(r0b, Wr0b);
    wt_oihw<128, 32, 9><<<144, blk, 0, stream>>>(r1a, Wr1a);
    wt_oihw<32, 128, 9><<<144, blk, 0, stream>>>(r1b, Wr1b);
    wt_oihw<128, 64, 1><<<32,  blk, 0, stream>>>(wp,  Wp);
    wt_oihw<64, 128, 9><<<288, blk, 0, stream>>>(dw1, Wd1);
    wt_oihw<128, 32, 9><<<144, blk, 0, stream>>>(dr0a, Wdr0a);
    wt_oihw<32, 128, 9><<<144, blk, 0, stream>>>(dr0b, Wdr0b);
    wt_oihw<128, 32, 9><<<144, blk, 0, stream>>>(dr1a, Wdr1a);
    wt_oihw<32, 128, 9><<<144, blk, 0, stream>>>(dr1b, Wdr1b);
    wt_tconv1<<<512, blk, 0, stream>>>(tw1, WT1);
    vq_prep<<<128, blk, 0, stream>>>(E, Ebf, eN);

    // ---- encoder ----
    conv1_k<<<dim3(32 * 128, 8), blk, 0, stream>>>(x, w1, b1, H1);
    conv_mfma2<64,128,2,1,0,16,false,true ,false><<<1024, blk, 0, stream>>>(H1, Wt2, b2, nullptr, H2, 128, 128);
    conv_mfma2<128,128,1,0,0, 9,false,false,false><<<1024, blk, 0, stream>>>(H2, Wt3, b3, nullptr, C, 64, 64);
    conv_mfma2<128, 32,1,0,0, 9,true ,true ,false><<<1024, blk, 0, stream>>>(C, Wr0a, nullptr, nullptr, F, 64, 64);
    conv_mfma2<32, 128,1,0,0, 9,false,false,true ><<<1024, blk, 0, stream>>>(F, Wr0b, nullptr, C, C, 64, 64);
    conv_mfma2<128, 32,1,0,0, 9,true ,true ,false><<<1024, blk, 0, stream>>>(C, Wr1a, nullptr, nullptr, F, 64, 64);
    conv_mfma2<32, 128,1,0,0, 9,false,true ,true ><<<1024, blk, 0, stream>>>(F, Wr1b, nullptr, C, C, 64, 64);
    conv_mfma2<128, 64,1,3,0, 1,false,false,false><<<1024, blk, 0, stream>>>(C, Wp, bp, nullptr, Z, 64, 64);

    // ---- VQ ----
    vq_mfma<<<2048, blk, 0, stream>>>(Z, Ebf, E, eN, ZQ, ST);

    // ---- decoder ----
    conv_mfma2<64,128,1,0,0, 9,false,false,false><<<1024, blk, 0, stream>>>(ZQ, Wd1, db1, nullptr, D, 64, 64);
    conv_mfma2<128, 32,1,0,0, 9,true ,true ,false><<<1024, blk, 0, stream>>>(D, Wdr0a, nullptr, nullptr, F, 64, 64);
    conv_mfma2<32, 128,1,0,0, 9,false,false,true ><<<1024, blk, 0, stream>>>(F, Wdr0b, nullptr, D, D, 64, 64);
    conv_mfma2<128, 32,1,0,0, 9,true ,true ,false><<<1024, blk, 0, stream>>>(D, Wdr1a, nullptr, nullptr, F, 64, 64);
    conv_mfma2<32, 128,1,0,0, 9,false,true ,true ><<<1024, blk, 0, stream>>>(F, Wdr1b, nullptr, D, D, 64, 64);
    conv_mfma2<128, 64,1,2,0, 4,false,true ,false><<<1024, blk, 0, stream>>>(D, WT1 + 0 * 32768, tb1, nullptr, T, 64, 64);
    conv_mfma2<128, 64,1,2,1, 4,false,true ,false><<<1024, blk, 0, stream>>>(D, WT1 + 1 * 32768, tb1, nullptr, T, 64, 64);
    conv_mfma2<128, 64,1,2,2, 4,false,true ,false><<<1024, blk, 0, stream>>>(D, WT1 + 2 * 32768, tb1, nullptr, T, 64, 64);
    conv_mfma2<128, 64,1,2,3, 4,false,true ,false><<<1024, blk, 0, stream>>>(D, WT1 + 3 * 32768, tb1, nullptr, T, 64, 64);
    convt2_k<<<32 * 256, blk, 0, stream>>>(T, tw2, tb2, out + 1);

    // ---- loss / perplexity ----
    finalize_kernel<<<1, 512, 0, stream>>>(ST, out, out_size - 1);
}

// Round 8
// 1255.811 us; speedup vs baseline: 26.9514x; 1.0576x over previous
//
#include <hip/hip_runtime.h>
#include <math.h>

typedef __attribute__((ext_vector_type(8))) short bf16x8;
typedef __attribute__((ext_vector_type(4))) float f32x4;

__device__ inline float bf2f(ushort u) {
    union { uint i; float f; } v; v.i = ((uint)u) << 16; return v.f;
}
__device__ inline ushort f2bf(float f) {
    union { float f; uint i; } v; v.f = f;
    uint b = v.i;
    b += 0x7FFFu + ((b >> 16) & 1u);      // RNE
    return (ushort)(b >> 16);
}
__device__ inline uint relu2bf(uint x) {
    uint s = x & 0x80008000u;
    uint m = (s >> 15) * 0xFFFFu;
    return x & ~m;
}

// ---------------------------------------------------------------------------
// Weight transforms -> bf16 [co][tap*CIN+ci]
// ---------------------------------------------------------------------------
template<int CIN, int COUT, int NT>
__global__ __launch_bounds__(256) void wt_oihw(const float* __restrict__ s, ushort* __restrict__ d) {
    int i = blockIdx.x * 256 + threadIdx.x;
    if (i >= COUT * NT * CIN) return;
    int co = i / (NT * CIN);
    int r  = i % (NT * CIN);
    int tap = r / CIN, ci = r % CIN;
    d[i] = f2bf(s[(co * CIN + ci) * NT + tap]);
}

// convT1 tw1 [128ci][64co][4][4] -> 4 classes [cls][64co][4tap*128ci]
__global__ __launch_bounds__(256) void wt_tconv1(const float* __restrict__ s, ushort* __restrict__ d) {
    int i = blockIdx.x * 256 + threadIdx.x;
    if (i >= 4 * 64 * 512) return;
    int cls = i >> 15;
    int co  = (i >> 9) & 63;
    int k   = i & 511;
    int tap = k >> 7, ci = k & 127;
    int a = tap >> 1, b = tap & 1;
    int ph = cls >> 1, pw = cls & 1;
    int kh = ph ? (a ? 2 : 0) : (a ? 3 : 1);
    int kw = pw ? (b ? 2 : 0) : (b ? 3 : 1);
    d[i] = f2bf(s[((ci * 64 + co) << 4) + kh * 4 + kw]);
}

// E -> bf16 copy + per-code squared norms
__global__ __launch_bounds__(256) void vq_prep(const float* __restrict__ E,
                                               ushort* __restrict__ Ebf, float* __restrict__ eN) {
    int i = blockIdx.x * 256 + threadIdx.x;
    if (i < 32768) Ebf[i] = f2bf(E[i]);
    if (i < 512) {
        float s = 0.f;
        #pragma unroll 8
        for (int d = 0; d < 64; ++d) { float x = E[i * 64 + d]; s = fmaf(x, x, s); }
        eN[i] = s;
    }
}

// ---------------------------------------------------------------------------
// Stage-once LDS-patch MFMA conv for 64x64 maps. Block = 2 output rows
// (128 px), grid = 32 img * 32 row-pairs = 1024. Patch = [PR][PC][CIN+8]
// staged ONCE (relu fused), then the whole K loop runs barrier-free:
// A-frag addr = uniform tap base + per-lane constant offset.
// NT=9 (3x3 p1, HALO=1) or NT=1 (1x1, HALO=0). wt: bf16 [COUT][NT*CIN].
// ---------------------------------------------------------------------------
template<int CIN, int COUT, int NT, int HALO, bool RELU_A, bool RELU_OUT, bool HAS_RES>
__global__ __launch_bounds__(256)
void conv_lds(const ushort* __restrict__ in, const ushort* __restrict__ wt,
              const float* __restrict__ bias, const ushort* __restrict__ res,
              ushort* __restrict__ out) {
    constexpr int K = NT * CIN;
    constexpr int KSTEPS = K / 32;
    constexpr int CSTEPS = CIN / 32;
    constexpr int PR = HALO ? 4 : 2;
    constexpr int PC = HALO ? 66 : 64;
    constexpr int CIP = CIN + 8;            // +16B => 4-bank skew per pixel
    constexpr int WM = (COUT == 128) ? 4 : 2;
    constexpr int WN = (COUT == 32) ? 2 : 4;
    constexpr int NC8 = CIN / 8;
    constexpr int NLD = PR * PC * NC8;

    __shared__ ushort sP[PR * PC * CIP];

    const int t = threadIdx.x;
    const int w = t >> 6, l = t & 63;
    const int bid = blockIdx.x;
    const int n = bid >> 5, R = bid & 31;

    const int m0 = (COUT == 128) ? 64 * (w >> 1) : 32 * w;
    const int n0 = (COUT == 128) ? 64 * (w & 1) : 0;

    // ---- stage patch (once) ----
    for (int i = t; i < NLD; i += 256) {
        const int c8  = i & (NC8 - 1);
        const int rem = i / NC8;
        const int pc  = rem % PC;
        const int pr  = rem / PC;
        const int grow = 2 * R - HALO + pr;
        const int gcol = pc - HALO;
        uint4 v = make_uint4(0u, 0u, 0u, 0u);
        if (!HALO || ((unsigned)grow < 64u && (unsigned)gcol < 64u))
            v = *reinterpret_cast<const uint4*>(
                in + (((long long)(n * 64 + grow)) * 64 + gcol) * CIN + c8 * 8);
        if (RELU_A) {
            v.x = relu2bf(v.x); v.y = relu2bf(v.y);
            v.z = relu2bf(v.z); v.w = relu2bf(v.w);
        }
        *reinterpret_cast<uint4*>(&sP[(pr * PC + pc) * CIP + c8 * 8]) = v;
    }
    __syncthreads();

    // per-lane constant A offsets
    int aoff[WM];
    #pragma unroll
    for (int mf = 0; mf < WM; ++mf) {
        const int px = m0 + mf * 16 + (l & 15);
        aoff[mf] = ((px >> 6) * PC + (px & 63)) * CIP + ((l >> 4) * 8);
    }

    f32x4 acc[WM][WN] = {};

    for (int ks = 0; ks < KSTEPS; ++ks) {
        const int tap = (CSTEPS == 1) ? ks : ks / CSTEPS;
        const int ci0 = (CSTEPS == 1) ? 0 : (ks % CSTEPS) * 32;
        int dh = 0, dw = 0;
        if (NT == 9) { dh = tap / 3 - 1; dw = tap % 3 - 1; }
        const int base = ((dh + HALO) * PC + (dw + HALO)) * CIP + ci0;

        bf16x8 bfr[WN];
        #pragma unroll
        for (int nf = 0; nf < WN; ++nf)
            bfr[nf] = *reinterpret_cast<const bf16x8*>(
                wt + (n0 + nf * 16 + (l & 15)) * K + ks * 32 + ((l >> 4) * 8));

        #pragma unroll
        for (int mf = 0; mf < WM; ++mf) {
            bf16x8 afr = *reinterpret_cast<const bf16x8*>(&sP[base + aoff[mf]]);
            #pragma unroll
            for (int nf = 0; nf < WN; ++nf)
                acc[mf][nf] = __builtin_amdgcn_mfma_f32_16x16x32_bf16(
                    afr, bfr[nf], acc[mf][nf], 0, 0, 0);
        }
    }

    // epilogue: C/D col=lane&15, row=(lane>>4)*4+r
    #pragma unroll
    for (int mf = 0; mf < WM; ++mf) {
        #pragma unroll
        for (int nf = 0; nf < WN; ++nf) {
            const int col = n0 + nf * 16 + (l & 15);
            const float bv = bias ? bias[col] : 0.f;
            #pragma unroll
            for (int r = 0; r < 4; ++r) {
                const int prow = m0 + mf * 16 + ((l >> 4) * 4) + r;
                const int orow = 2 * R + (prow >> 6);
                const int ocol = prow & 63;
                const long long oidx = (((long long)(n * 64 + orow)) * 64 + ocol) * COUT + col;
                float v = acc[mf][nf][r] + bv;
                if (HAS_RES) v += bf2f(res[oidx]);
                if (RELU_OUT) v = fmaxf(v, 0.f);
                out[oidx] = f2bf(v);
            }
        }
    }
}

// ---------------------------------------------------------------------------
// convT1 merged: 128->64, k4 s2 p1, all 4 parity classes in one kernel.
// Block = input-row pair R (patch rows 2R-1..2R+2) -> output rows 4R..4R+3.
// Wave w = class (ph,pw); each wave: 128 px x 64 co, K=512, barrier-free.
// wt: [cls][64co][4tap*128ci], taps ordered as wt_tconv1.
// ---------------------------------------------------------------------------
__global__ __launch_bounds__(256)
void convt1_lds(const ushort* __restrict__ in, const ushort* __restrict__ wt,
                const float* __restrict__ bias, ushort* __restrict__ out) {
    constexpr int CIN = 128, CIP = 136, PC = 66;
    __shared__ ushort sP[4 * PC * CIP];

    const int t = threadIdx.x;
    const int w = t >> 6, l = t & 63;
    const int bid = blockIdx.x;
    const int n = bid >> 5, R = bid & 31;

    for (int i = t; i < 4 * PC * 16; i += 256) {
        const int c8  = i & 15;
        const int rem = i >> 4;
        const int pc  = rem % PC;
        const int pr  = rem / PC;
        const int grow = 2 * R - 1 + pr;
        const int gcol = pc - 1;
        uint4 v = make_uint4(0u, 0u, 0u, 0u);
        if ((unsigned)grow < 64u && (unsigned)gcol < 64u)
            v = *reinterpret_cast<const uint4*>(
                in + (((long long)(n * 64 + grow)) * 64 + gcol) * CIN + c8 * 8);
        *reinterpret_cast<uint4*>(&sP[(pr * PC + pc) * CIP + c8 * 8]) = v;
    }
    __syncthreads();

    const int ph = w >> 1, pw = w & 1;
    const ushort* wc = wt + w * 32768;

    int aoff[8];
    #pragma unroll
    for (int mf = 0; mf < 8; ++mf) {
        const int px = mf * 16 + (l & 15);
        aoff[mf] = ((px >> 6) * PC + (px & 63)) * CIP + ((l >> 4) * 8);
    }

    f32x4 acc[8][4] = {};

    for (int ks = 0; ks < 16; ++ks) {
        const int tap = ks >> 2, ci0 = (ks & 3) * 32;
        const int a = tap >> 1, b = tap & 1;
        const int dh = ph ? 1 - a : -a;
        const int dw = pw ? 1 - b : -b;
        const int base = ((dh + 1) * PC + (dw + 1)) * CIP + ci0;

        bf16x8 bfr[4];
        #pragma unroll
        for (int nf = 0; nf < 4; ++nf)
            bfr[nf] = *reinterpret_cast<const bf16x8*>(
                wc + (nf * 16 + (l & 15)) * 512 + ks * 32 + ((l >> 4) * 8));

        #pragma unroll
        for (int mf = 0; mf < 8; ++mf) {
            bf16x8 afr = *reinterpret_cast<const bf16x8*>(&sP[base + aoff[mf]]);
            #pragma unroll
            for (int nf = 0; nf < 4; ++nf)
                acc[mf][nf] = __builtin_amdgcn_mfma_f32_16x16x32_bf16(
                    afr, bfr[nf], acc[mf][nf], 0, 0, 0);
        }
    }

    #pragma unroll
    for (int mf = 0; mf < 8; ++mf) {
        #pragma unroll
        for (int nf = 0; nf < 4; ++nf) {
            const int col = nf * 16 + (l & 15);
            const float bv = bias[col];
            #pragma unroll
            for (int r = 0; r < 4; ++r) {
                const int prow = mf * 16 + ((l >> 4) * 4) + r;
                const int orow = 2 * R + (prow >> 6);
                const int ocol = prow & 63;
                const long long oidx =
                    (((long long)(n * 128 + 2 * orow + ph)) * 128 + 2 * ocol + pw) * 64 + col;
                float v = fmaxf(acc[mf][nf][r] + bv, 0.f);
                out[oidx] = f2bf(v);
            }
        }
    }
}

// ---------------------------------------------------------------------------
// conv2 (4x4 s2, 128x128 -> 64x64): keep v2 gather structure.
// ---------------------------------------------------------------------------
template<int CIN, int COUT, bool RELU_OUT>
__global__ __launch_bounds__(256)
void conv_s2(const ushort* __restrict__ in, const ushort* __restrict__ wt,
             const float* __restrict__ bias, ushort* __restrict__ out,
             int Hin, int Win) {
    constexpr int K = 16 * CIN;
    constexpr int KSTEPS = K / 32;
    constexpr int CSTEPS = CIN / 32;
    constexpr int WM = 4, WN = 4;

    __shared__ ushort sA[2][128 * 40];

    const int t = threadIdx.x;
    const int w = t >> 6, l = t & 63;
    const int bid = blockIdx.x;
    const int n = bid >> 5, R = bid & 31;

    const int m0 = 64 * (w >> 1);
    const int n0 = 64 * (w & 1);

    const int gpx  = t >> 1;
    const int gk   = (t & 1) * 16;
    const int grow = 2 * R + (gpx >> 6);
    const int gcol = gpx & 63;

    auto gather = [&](int ks, uint4& g0, uint4& g1) {
        int tap, ci0;
        if (CSTEPS == 1) { tap = ks; ci0 = 0; }
        else             { tap = ks / CSTEPS; ci0 = (ks % CSTEPS) * 32; }
        const int dh = tap / 4 - 1, dw = tap % 4 - 1;
        const int ih = 2 * grow + dh, iw = 2 * gcol + dw;
        g0 = make_uint4(0u, 0u, 0u, 0u); g1 = g0;
        if ((unsigned)ih < (unsigned)Hin && (unsigned)iw < (unsigned)Win) {
            const ushort* p = in + (((long long)(n * Hin + ih)) * Win + iw) * CIN + ci0 + gk;
            g0 = *reinterpret_cast<const uint4*>(p);
            g1 = *reinterpret_cast<const uint4*>(p + 8);
        }
    };

    f32x4 acc[WM][WN] = {};

    uint4 g0, g1;
    gather(0, g0, g1);
    *reinterpret_cast<uint4*>(&sA[0][gpx * 40 + gk])     = g0;
    *reinterpret_cast<uint4*>(&sA[0][gpx * 40 + gk + 8]) = g1;
    __syncthreads();

    int cur = 0;
    for (int ks = 0; ks < KSTEPS; ++ks) {
        const bool more = (ks + 1 < KSTEPS);
        uint4 h0, h1;
        if (more) gather(ks + 1, h0, h1);

        bf16x8 bfr[WN];
        #pragma unroll
        for (int nf = 0; nf < WN; ++nf)
            bfr[nf] = *reinterpret_cast<const bf16x8*>(
                wt + (n0 + nf * 16 + (l & 15)) * K + ks * 32 + ((l >> 4) * 8));

        bf16x8 afr[WM];
        #pragma unroll
        for (int mf = 0; mf < WM; ++mf)
            afr[mf] = *reinterpret_cast<const bf16x8*>(
                &sA[cur][(m0 + mf * 16 + (l & 15)) * 40 + ((l >> 4) * 8)]);

        #pragma unroll
        for (int mf = 0; mf < WM; ++mf)
            #pragma unroll
            for (int nf = 0; nf < WN; ++nf)
                acc[mf][nf] = __builtin_amdgcn_mfma_f32_16x16x32_bf16(
                    afr[mf], bfr[nf], acc[mf][nf], 0, 0, 0);

        if (more) {
            *reinterpret_cast<uint4*>(&sA[cur ^ 1][gpx * 40 + gk])     = h0;
            *reinterpret_cast<uint4*>(&sA[cur ^ 1][gpx * 40 + gk + 8]) = h1;
            __syncthreads();
            cur ^= 1;
        }
    }

    #pragma unroll
    for (int mf = 0; mf < WM; ++mf) {
        #pragma unroll
        for (int nf = 0; nf < WN; ++nf) {
            const int col = n0 + nf * 16 + (l & 15);
            const float bv = bias[col];
            #pragma unroll
            for (int r = 0; r < 4; ++r) {
                const int prow = m0 + mf * 16 + ((l >> 4) * 4) + r;
                const int orow = 2 * R + (prow >> 6);
                const int ocol = prow & 63;
                const long long oidx = (((long long)(n * 64 + orow)) * 64 + ocol) * COUT + col;
                float v = acc[mf][nf][r] + bv;
                if (RELU_OUT) v = fmaxf(v, 0.f);
                out[oidx] = f2bf(v);
            }
        }
    }
}

// ---------------------------------------------------------------------------
// conv1: 3->64, 4x4 s2 pad1, fp32 NCHW in -> bf16 NHWC out, relu.
// sW transposed [k][co] -> conflict-free weight reads.
// ---------------------------------------------------------------------------
__global__ __launch_bounds__(256)
void conv1_k(const float* __restrict__ x, const float* __restrict__ w1,
             const float* __restrict__ b1, ushort* __restrict__ out) {
    __shared__ float sIn[3 * 4 * 36];
    __shared__ float sW[48 * 64];           // [k][co]
    const int t = threadIdx.x;
    const int bid = blockIdx.x;
    const int n = bid >> 7, oh = bid & 127;
    const int ow0 = blockIdx.y * 16;

    for (int i = t; i < 3072; i += 256) {
        int co = i / 48, k = i % 48;
        sW[k * 64 + co] = w1[i];
    }
    for (int i = t; i < 3 * 4 * 34; i += 256) {
        int ci = i / 136, r = i - ci * 136;
        int r4 = r / 34, iwl = r % 34;
        int ih = 2 * oh - 1 + r4;
        int iw = 2 * ow0 - 1 + iwl;
        float v = 0.f;
        if ((unsigned)ih < 256u && (unsigned)iw < 256u)
            v = x[((n * 3 + ci) * 256 + ih) * 256 + iw];
        sIn[ci * 144 + r4 * 36 + iwl] = v;
    }
    __syncthreads();

    const int co = t & 63, j = t >> 6;
    float wr[48];
    #pragma unroll
    for (int i = 0; i < 48; ++i) wr[i] = sW[i * 64 + co];
    const float bv = b1[co];

    #pragma unroll
    for (int q = 0; q < 4; ++q) {
        const int owl = j * 4 + q;
        float acc = bv;
        #pragma unroll
        for (int ci = 0; ci < 3; ++ci)
            #pragma unroll
            for (int kh = 0; kh < 4; ++kh)
                #pragma unroll
                for (int kw = 0; kw < 4; ++kw)
                    acc = fmaf(sIn[ci * 144 + kh * 36 + 2 * owl + kw],
                               wr[ci * 16 + kh * 4 + kw], acc);
        acc = fmaxf(acc, 0.f);
        out[(((long long)(n * 128 + oh)) * 128 + ow0 + owl) * 64 + co] = f2bf(acc);
    }
}

// ---------------------------------------------------------------------------
// convT2: 64->3, k4 s2 p1, bf16 NHWC in [32,128,128,64] -> fp32 NCHW out.
// ---------------------------------------------------------------------------
__global__ __launch_bounds__(256)
void convt2_k(const ushort* __restrict__ in, const float* __restrict__ tw2,
              const float* __restrict__ tb2, float* __restrict__ out) {
    __shared__ float sW[64 * 48];           // [ci][co][16]
    const int t = threadIdx.x;
    for (int i = t; i < 3072; i += 256) sW[i] = tw2[i];
    __syncthreads();

    const int bid = blockIdx.x;
    const int n = bid >> 8, oh = bid & 255;
    const int ow = t;
    const int khA = (oh + 1) & 1, ihA = (oh + 1) >> 1;
    const int kwA = (ow + 1) & 1, iwA = (ow + 1) >> 1;

    float a0 = tb2[0], a1 = tb2[1], a2 = tb2[2];
    #pragma unroll
    for (int a = 0; a < 2; ++a) {
        const int ih = ihA - a;
        if ((unsigned)ih >= 128u) continue;
        const int kh = khA + 2 * a;
        #pragma unroll
        for (int b = 0; b < 2; ++b) {
            const int iw = iwA - b;
            if ((unsigned)iw >= 128u) continue;
            const int kw = kwA + 2 * b;
            const ushort* src = in + (((long long)(n * 128 + ih)) * 128 + iw) * 64;
            const int k = kh * 4 + kw;
            #pragma unroll
            for (int c8 = 0; c8 < 8; ++c8) {
                uint4 v = *reinterpret_cast<const uint4*>(src + c8 * 8);
                const uint u[4] = {v.x, v.y, v.z, v.w};
                #pragma unroll
                for (int p = 0; p < 4; ++p) {
                    union { uint i; float f; } lo, hi;
                    lo.i = u[p] << 16; hi.i = u[p] & 0xFFFF0000u;
                    const int ci = c8 * 8 + p * 2;
                    a0 = fmaf(lo.f, sW[ci * 48 + 0 * 16 + k], a0);
                    a1 = fmaf(lo.f, sW[ci * 48 + 1 * 16 + k], a1);
                    a2 = fmaf(lo.f, sW[ci * 48 + 2 * 16 + k], a2);
                    a0 = fmaf(hi.f, sW[(ci + 1) * 48 + 0 * 16 + k], a0);
                    a1 = fmaf(hi.f, sW[(ci + 1) * 48 + 1 * 16 + k], a1);
                    a2 = fmaf(hi.f, sW[(ci + 1) * 48 + 2 * 16 + k], a2);
                }
            }
        }
    }
    const long long px = (long long)oh * 256 + ow;
    out[(long long)(n * 3 + 0) * 65536 + px] = a0;
    out[(long long)(n * 3 + 1) * 65536 + px] = a1;
    out[(long long)(n * 3 + 2) * 65536 + px] = a2;
}

// ---------------------------------------------------------------------------
// MFMA VQ (unchanged from round 6).
// ---------------------------------------------------------------------------
__global__ __launch_bounds__(256)
void vq_mfma(const ushort* __restrict__ z, const ushort* __restrict__ Ebf,
             const float* __restrict__ E, const float* __restrict__ eN,
             ushort* __restrict__ zq, float* __restrict__ stats) {
    __shared__ ushort sZ[64 * 72];
    __shared__ float sEN[512];
    __shared__ float sV[64 * 4];
    __shared__ int   sI[64 * 4];
    __shared__ int   sIdx[64];
    __shared__ unsigned shist[512];
    __shared__ float red[256];

    const int t = threadIdx.x;
    const int w = t >> 6, l = t & 63;
    const long long p0 = (long long)blockIdx.x * 64;

    {
        const int px = t >> 2, koff = (t & 3) * 16;
        const ushort* p = z + (p0 + px) * 64 + koff;
        uint4 a0 = *reinterpret_cast<const uint4*>(p);
        uint4 a1 = *reinterpret_cast<const uint4*>(p + 8);
        *reinterpret_cast<uint4*>(&sZ[px * 72 + koff])     = a0;
        *reinterpret_cast<uint4*>(&sZ[px * 72 + koff + 8]) = a1;
        sEN[t] = eN[t]; sEN[t + 256] = eN[t + 256];
        shist[t] = 0u; shist[t + 256] = 0u;
    }
    __syncthreads();

    f32x4 acc[4][8] = {};
    #pragma unroll
    for (int ks = 0; ks < 2; ++ks) {
        bf16x8 bfr[8];
        #pragma unroll
        for (int nf = 0; nf < 8; ++nf)
            bfr[nf] = *reinterpret_cast<const bf16x8*>(
                Ebf + (w * 128 + nf * 16 + (l & 15)) * 64 + ks * 32 + ((l >> 4) * 8));
        #pragma unroll
        for (int mf = 0; mf < 4; ++mf) {
            bf16x8 afr = *reinterpret_cast<const bf16x8*>(
                &sZ[(mf * 16 + (l & 15)) * 72 + ks * 32 + ((l >> 4) * 8)]);
            #pragma unroll
            for (int nf = 0; nf < 8; ++nf)
                acc[mf][nf] = __builtin_amdgcn_mfma_f32_16x16x32_bf16(
                    afr, bfr[nf], acc[mf][nf], 0, 0, 0);
        }
    }

    float eNr[8];
    #pragma unroll
    for (int nf = 0; nf < 8; ++nf) eNr[nf] = sEN[w * 128 + nf * 16 + (l & 15)];

    #pragma unroll
    for (int mf = 0; mf < 4; ++mf) {
        #pragma unroll
        for (int r = 0; r < 4; ++r) {
            float best = 3.4e38f; int bidx = 0;
            #pragma unroll
            for (int nf = 0; nf < 8; ++nf) {
                float s = eNr[nf] - 2.f * acc[mf][nf][r];
                int   c = w * 128 + nf * 16 + (l & 15);
                if (s < best || (s == best && c < bidx)) { best = s; bidx = c; }
            }
            #pragma unroll
            for (int off = 1; off < 16; off <<= 1) {
                float ov = __shfl_xor(best, off);
                int   oi = __shfl_xor(bidx, off);
                if (ov < best || (ov == best && oi < bidx)) { best = ov; bidx = oi; }
            }
            if ((l & 15) == 0) {
                const int px = mf * 16 + ((l >> 4) * 4) + r;
                sV[px * 4 + w] = best; sI[px * 4 + w] = bidx;
            }
        }
    }
    __syncthreads();

    if (t < 64) {
        float best = sV[t * 4]; int bidx = sI[t * 4];
        #pragma unroll
        for (int w2 = 1; w2 < 4; ++w2) {
            float v = sV[t * 4 + w2]; int c = sI[t * 4 + w2];
            if (v < best || (v == best && c < bidx)) { best = v; bidx = c; }
        }
        sIdx[t] = bidx;
        atomicAdd(&shist[bidx], 1u);
    }
    __syncthreads();

    {
        const int px = t >> 2, doff = (t & 3) * 16;
        const int idx = sIdx[px];
        const float* e = E + idx * 64 + doff;
        float dist = 0.f;
        uint4 pk4[2];
        ushort* pk = reinterpret_cast<ushort*>(pk4);
        #pragma unroll
        for (int j = 0; j < 16; ++j) {
            float ev = e[j];
            float zv = bf2f(sZ[px * 72 + doff + j]);
            float df = ev - zv;
            dist = fmaf(df, df, dist);
            pk[j] = f2bf(ev);
        }
        *reinterpret_cast<uint4*>(zq + (p0 + px) * 64 + doff)     = pk4[0];
        *reinterpret_cast<uint4*>(zq + (p0 + px) * 64 + doff + 8) = pk4[1];
        red[t] = dist;
    }
    __syncthreads();
    for (int s = 128; s > 0; s >>= 1) {
        if (t < s) red[t] += red[t + s];
        __syncthreads();
    }
    if (t == 0) atomicAdd(&stats[0], red[0]);
    for (int i = t; i < 512; i += 256) {
        unsigned c = shist[i];
        if (c) atomicAdd(&stats[1 + i], (float)c);
    }
}

__global__ __launch_bounds__(512)
void finalize_kernel(const float* __restrict__ stats, float* __restrict__ out, int plast) {
    __shared__ float red[512];
    int t = threadIdx.x;
    float c = stats[1 + t];
    float p = c * (1.f / 131072.f);
    red[t] = p * logf(p + 1e-10f);
    __syncthreads();
    for (int s = 256; s > 0; s >>= 1) {
        if (t < s) red[t] += red[t + s];
        __syncthreads();
    }
    if (t == 0) {
        out[plast] = expf(-red[0]);
        out[0] = 7.6f * stats[0] * (1.f / 8388608.f);
    }
}

// ---------------------------------------------------------------------------
extern "C" void kernel_launch(void* const* d_in, const int* in_sizes, int n_in,
                              void* d_out, int out_size, void* d_ws, size_t ws_size,
                              hipStream_t stream) {
    (void)in_sizes; (void)n_in; (void)ws_size;
    const float* x   = (const float*)d_in[0];
    const float* w1  = (const float*)d_in[1];
    const float* b1  = (const float*)d_in[2];
    const float* w2  = (const float*)d_in[3];
    const float* b2  = (const float*)d_in[4];
    const float* w3  = (const float*)d_in[5];
    const float* b3  = (const float*)d_in[6];
    const float* r0a = (const float*)d_in[7];
    const float* r0b = (const float*)d_in[8];
    const float* r1a = (const float*)d_in[9];
    const float* r1b = (const float*)d_in[10];
    const float* wp  = (const float*)d_in[11];
    const float* bp  = (const float*)d_in[12];
    const float* E   = (const float*)d_in[13];
    const float* dw1 = (const float*)d_in[14];
    const float* db1 = (const float*)d_in[15];
    const float* dr0a= (const float*)d_in[16];
    const float* dr0b= (const float*)d_in[17];
    const float* dr1a= (const float*)d_in[18];
    const float* dr1b= (const float*)d_in[19];
    const float* tw1 = (const float*)d_in[20];
    const float* tb1 = (const float*)d_in[21];
    const float* tw2 = (const float*)d_in[22];
    const float* tb2 = (const float*)d_in[23];

    float* out = (float*)d_out;
    ushort* ws = (ushort*)d_ws;

    ushort* H1 = ws;                  // [32,128,128,64] ; later convT1 out T
    ushort* H2 = ws + 33554432;       // [32,64,64,128]  ; later decoder D
    ushort* C  = ws + 50331648;       // [32,64,64,128]
    ushort* F  = ws + 67108864;       // [32,64,64,32]  res temp
    ushort* Z  = ws + 71303168;       // [131072,64]
    ushort* ZQ = ws + 79691776;       // [131072,64]
    ushort* W0 = ws + 88080384;       // weight block
    ushort* Wt2   = W0;               // 131072
    ushort* Wt3   = W0 + 131072;      // 147456
    ushort* Wr0a  = W0 + 278528;
    ushort* Wr0b  = W0 + 315392;
    ushort* Wr1a  = W0 + 352256;
    ushort* Wr1b  = W0 + 389120;
    ushort* Wp    = W0 + 425984;
    ushort* Wd1   = W0 + 434176;
    ushort* Wdr0a = W0 + 507904;
    ushort* Wdr0b = W0 + 544768;
    ushort* Wdr1a = W0 + 581632;
    ushort* Wdr1b = W0 + 618496;
    ushort* WT1   = W0 + 655360;      // 131072 -> ends W0+786432
    ushort* Ebf   = W0 + 786432;      // 32768
    float*  eN    = (float*)(W0 + 819200);   // 512 floats
    float*  ST    = (float*)(W0 + 820224);   // 513 floats
    ushort* T = H1;
    ushort* D = H2;

    hipMemsetAsync(ST, 0, 513 * sizeof(float), stream);

    dim3 blk(256);
    wt_oihw<64, 128,16><<<512, blk, 0, stream>>>(w2,  Wt2);
    wt_oihw<128,128, 9><<<576, blk, 0, stream>>>(w3,  Wt3);
    wt_oihw<128, 32, 9><<<144, blk, 0, stream>>>(r0a, Wr0a);
    wt_oihw<32, 128, 9><<<144, blk, 0, stream>>>(r0b, Wr0b);
    wt_oihw<128, 32, 9><<<144, blk, 0, stream>>>(r1a, Wr1a);
    wt_oihw<32, 128, 9><<<144, blk, 0, stream>>>(r1b, Wr1b);
    wt_oihw<128, 64, 1><<<32,  blk, 0, stream>>>(wp,  Wp);
    wt_oihw<64, 128, 9><<<288, blk, 0, stream>>>(dw1, Wd1);
    wt_oihw<128, 32, 9><<<144, blk, 0, stream>>>(dr0a, Wdr0a);
    wt_oihw<32, 128, 9><<<144, blk, 0, stream>>>(dr0b, Wdr0b);
    wt_oihw<128, 32, 9><<<144, blk, 0, stream>>>(dr1a, Wdr1a);
    wt_oihw<32, 128, 9><<<144, blk, 0, stream>>>(dr1b, Wdr1b);
    wt_tconv1<<<512, blk, 0, stream>>>(tw1, WT1);
    vq_prep<<<128, blk, 0, stream>>>(E, Ebf, eN);

    // ---- encoder ----
    conv1_k<<<dim3(32 * 128, 8), blk, 0, stream>>>(x, w1, b1, H1);
    conv_s2<64,128,true><<<1024, blk, 0, stream>>>(H1, Wt2, b2, H2, 128, 128);
    conv_lds<128,128,9,1,false,false,false><<<1024, blk, 0, stream>>>(H2, Wt3, b3, nullptr, C);
    conv_lds<128, 32,9,1,true ,true ,false><<<1024, blk, 0, stream>>>(C, Wr0a, nullptr, nullptr, F);
    conv_lds<32, 128,9,1,false,false,true ><<<1024, blk, 0, stream>>>(F, Wr0b, nullptr, C, C);
    conv_lds<128, 32,9,1,true ,true ,false><<<1024, blk, 0, stream>>>(C, Wr1a, nullptr, nullptr, F);
    conv_lds<32, 128,9,1,false,true ,true ><<<1024, blk, 0, stream>>>(F, Wr1b, nullptr, C, C);
    conv_lds<128, 64,1,0,false,false,false><<<1024, blk, 0, stream>>>(C, Wp, bp, nullptr, Z);

    // ---- VQ ----
    vq_mfma<<<2048, blk, 0, stream>>>(Z, Ebf, E, eN, ZQ, ST);

    // ---- decoder ----
    conv_lds<64, 128,9,1,false,false,false><<<1024, blk, 0, stream>>>(ZQ, Wd1, db1, nullptr, D);
    conv_lds<128, 32,9,1,true ,true ,false><<<1024, blk, 0, stream>>>(D, Wdr0a, nullptr, nullptr, F);
    conv_lds<32, 128,9,1,false,false,true ><<<1024, blk, 0, stream>>>(F, Wdr0b, nullptr, D, D);
    conv_lds<128, 32,9,1,true ,true ,false><<<1024, blk, 0, stream>>>(D, Wdr1a, nullptr, nullptr, F);
    conv_lds<32, 128,9,1,false,true ,true ><<<1024, blk, 0, stream>>>(F, Wdr1b, nullptr, D, D);
    convt1_lds<<<1024, blk, 0, stream>>>(D, WT1, tb1, T);
    convt2_k<<<32 * 256, blk, 0, stream>>>(T, tw2, tb2, out + 1);

    // ---- loss / perplexity ----
    finalize_kernel<<<1, 512, 0, stream>>>(ST, out, out_size - 1);
}

// Round 9
// 1231.650 us; speedup vs baseline: 27.4801x; 1.0196x over previous
//
#include <hip/hip_runtime.h>
#include <math.h>

typedef __attribute__((ext_vector_type(8))) short bf16x8;
typedef __attribute__((ext_vector_type(4))) float f32x4;

__device__ inline float bf2f(ushort u) {
    union { uint i; float f; } v; v.i = ((uint)u) << 16; return v.f;
}
__device__ inline ushort f2bf(float f) {
    union { float f; uint i; } v; v.f = f;
    uint b = v.i;
    b += 0x7FFFu + ((b >> 16) & 1u);      // RNE
    return (ushort)(b >> 16);
}
__device__ inline uint relu2bf(uint x) {
    uint s = x & 0x80008000u;
    uint m = (s >> 15) * 0xFFFFu;
    return x & ~m;
}

// ---------------------------------------------------------------------------
// Weight transforms -> bf16 [co][tap*CIN+ci]
// ---------------------------------------------------------------------------
template<int CIN, int COUT, int NT>
__global__ __launch_bounds__(256) void wt_oihw(const float* __restrict__ s, ushort* __restrict__ d) {
    int i = blockIdx.x * 256 + threadIdx.x;
    if (i >= COUT * NT * CIN) return;
    int co = i / (NT * CIN);
    int r  = i % (NT * CIN);
    int tap = r / CIN, ci = r % CIN;
    d[i] = f2bf(s[(co * CIN + ci) * NT + tap]);
}

// convT1 tw1 [128ci][64co][4][4] -> 4 classes [cls][64co][4tap*128ci]
__global__ __launch_bounds__(256) void wt_tconv1(const float* __restrict__ s, ushort* __restrict__ d) {
    int i = blockIdx.x * 256 + threadIdx.x;
    if (i >= 4 * 64 * 512) return;
    int cls = i >> 15;
    int co  = (i >> 9) & 63;
    int k   = i & 511;
    int tap = k >> 7, ci = k & 127;
    int a = tap >> 1, b = tap & 1;
    int ph = cls >> 1, pw = cls & 1;
    int kh = ph ? (a ? 2 : 0) : (a ? 3 : 1);
    int kw = pw ? (b ? 2 : 0) : (b ? 3 : 1);
    d[i] = f2bf(s[((ci * 64 + co) << 4) + kh * 4 + kw]);
}

// E -> bf16 copy + per-code squared norms
__global__ __launch_bounds__(256) void vq_prep(const float* __restrict__ E,
                                               ushort* __restrict__ Ebf, float* __restrict__ eN) {
    int i = blockIdx.x * 256 + threadIdx.x;
    if (i < 32768) Ebf[i] = f2bf(E[i]);
    if (i < 512) {
        float s = 0.f;
        #pragma unroll 8
        for (int d = 0; d < 64; ++d) { float x = E[i * 64 + d]; s = fmaf(x, x, s); }
        eN[i] = s;
    }
}

// ---------------------------------------------------------------------------
// Stage-once LDS-patch MFMA conv for 64x64 maps. Block = 2 output rows
// (128 px), grid = 32 img * 32 row-pairs = 1024. Patch = [PR][PC][CIN+8]
// staged ONCE (relu fused), then the whole K loop runs barrier-free:
// A-frag addr = uniform tap base + per-lane constant offset.
// NT=9 (3x3 p1, HALO=1) or NT=1 (1x1, HALO=0). wt: bf16 [COUT][NT*CIN].
// ---------------------------------------------------------------------------
template<int CIN, int COUT, int NT, int HALO, bool RELU_A, bool RELU_OUT, bool HAS_RES>
__global__ __launch_bounds__(256)
void conv_lds(const ushort* __restrict__ in, const ushort* __restrict__ wt,
              const float* __restrict__ bias, const ushort* __restrict__ res,
              ushort* __restrict__ out) {
    constexpr int K = NT * CIN;
    constexpr int KSTEPS = K / 32;
    constexpr int CSTEPS = CIN / 32;
    constexpr int PR = HALO ? 4 : 2;
    constexpr int PC = HALO ? 66 : 64;
    constexpr int CIP = CIN + 8;            // +16B => 4-bank skew per pixel
    constexpr int WM = (COUT == 128) ? 4 : 2;
    constexpr int WN = (COUT == 32) ? 2 : 4;
    constexpr int NC8 = CIN / 8;
    constexpr int NLD = PR * PC * NC8;

    __shared__ ushort sP[PR * PC * CIP];

    const int t = threadIdx.x;
    const int w = t >> 6, l = t & 63;
    const int bid = blockIdx.x;
    const int n = bid >> 5, R = bid & 31;

    const int m0 = (COUT == 128) ? 64 * (w >> 1) : 32 * w;
    const int n0 = (COUT == 128) ? 64 * (w & 1) : 0;

    // ---- stage patch (once) ----
    for (int i = t; i < NLD; i += 256) {
        const int c8  = i & (NC8 - 1);
        const int rem = i / NC8;
        const int pc  = rem % PC;
        const int pr  = rem / PC;
        const int grow = 2 * R - HALO + pr;
        const int gcol = pc - HALO;
        uint4 v = make_uint4(0u, 0u, 0u, 0u);
        if (!HALO || ((unsigned)grow < 64u && (unsigned)gcol < 64u))
            v = *reinterpret_cast<const uint4*>(
                in + (((long long)(n * 64 + grow)) * 64 + gcol) * CIN + c8 * 8);
        if (RELU_A) {
            v.x = relu2bf(v.x); v.y = relu2bf(v.y);
            v.z = relu2bf(v.z); v.w = relu2bf(v.w);
        }
        *reinterpret_cast<uint4*>(&sP[(pr * PC + pc) * CIP + c8 * 8]) = v;
    }
    __syncthreads();

    // per-lane constant A offsets
    int aoff[WM];
    #pragma unroll
    for (int mf = 0; mf < WM; ++mf) {
        const int px = m0 + mf * 16 + (l & 15);
        aoff[mf] = ((px >> 6) * PC + (px & 63)) * CIP + ((l >> 4) * 8);
    }

    f32x4 acc[WM][WN] = {};

    for (int ks = 0; ks < KSTEPS; ++ks) {
        const int tap = (CSTEPS == 1) ? ks : ks / CSTEPS;
        const int ci0 = (CSTEPS == 1) ? 0 : (ks % CSTEPS) * 32;
        int dh = 0, dw = 0;
        if (NT == 9) { dh = tap / 3 - 1; dw = tap % 3 - 1; }
        const int base = ((dh + HALO) * PC + (dw + HALO)) * CIP + ci0;

        bf16x8 bfr[WN];
        #pragma unroll
        for (int nf = 0; nf < WN; ++nf)
            bfr[nf] = *reinterpret_cast<const bf16x8*>(
                wt + (n0 + nf * 16 + (l & 15)) * K + ks * 32 + ((l >> 4) * 8));

        #pragma unroll
        for (int mf = 0; mf < WM; ++mf) {
            bf16x8 afr = *reinterpret_cast<const bf16x8*>(&sP[base + aoff[mf]]);
            #pragma unroll
            for (int nf = 0; nf < WN; ++nf)
                acc[mf][nf] = __builtin_amdgcn_mfma_f32_16x16x32_bf16(
                    afr, bfr[nf], acc[mf][nf], 0, 0, 0);
        }
    }

    // epilogue: C/D col=lane&15, row=(lane>>4)*4+r
    #pragma unroll
    for (int mf = 0; mf < WM; ++mf) {
        #pragma unroll
        for (int nf = 0; nf < WN; ++nf) {
            const int col = n0 + nf * 16 + (l & 15);
            const float bv = bias ? bias[col] : 0.f;
            #pragma unroll
            for (int r = 0; r < 4; ++r) {
                const int prow = m0 + mf * 16 + ((l >> 4) * 4) + r;
                const int orow = 2 * R + (prow >> 6);
                const int ocol = prow & 63;
                const long long oidx = (((long long)(n * 64 + orow)) * 64 + ocol) * COUT + col;
                float v = acc[mf][nf][r] + bv;
                if (HAS_RES) v += bf2f(res[oidx]);
                if (RELU_OUT) v = fmaxf(v, 0.f);
                out[oidx] = f2bf(v);
            }
        }
    }
}

// ---------------------------------------------------------------------------
// convT1 merged: 128->64, k4 s2 p1, all 4 parity classes in one kernel.
// ---------------------------------------------------------------------------
__global__ __launch_bounds__(256)
void convt1_lds(const ushort* __restrict__ in, const ushort* __restrict__ wt,
                const float* __restrict__ bias, ushort* __restrict__ out) {
    constexpr int CIN = 128, CIP = 136, PC = 66;
    __shared__ ushort sP[4 * PC * CIP];

    const int t = threadIdx.x;
    const int w = t >> 6, l = t & 63;
    const int bid = blockIdx.x;
    const int n = bid >> 5, R = bid & 31;

    for (int i = t; i < 4 * PC * 16; i += 256) {
        const int c8  = i & 15;
        const int rem = i >> 4;
        const int pc  = rem % PC;
        const int pr  = rem / PC;
        const int grow = 2 * R - 1 + pr;
        const int gcol = pc - 1;
        uint4 v = make_uint4(0u, 0u, 0u, 0u);
        if ((unsigned)grow < 64u && (unsigned)gcol < 64u)
            v = *reinterpret_cast<const uint4*>(
                in + (((long long)(n * 64 + grow)) * 64 + gcol) * CIN + c8 * 8);
        *reinterpret_cast<uint4*>(&sP[(pr * PC + pc) * CIP + c8 * 8]) = v;
    }
    __syncthreads();

    const int ph = w >> 1, pw = w & 1;
    const ushort* wc = wt + w * 32768;

    int aoff[8];
    #pragma unroll
    for (int mf = 0; mf < 8; ++mf) {
        const int px = mf * 16 + (l & 15);
        aoff[mf] = ((px >> 6) * PC + (px & 63)) * CIP + ((l >> 4) * 8);
    }

    f32x4 acc[8][4] = {};

    for (int ks = 0; ks < 16; ++ks) {
        const int tap = ks >> 2, ci0 = (ks & 3) * 32;
        const int a = tap >> 1, b = tap & 1;
        const int dh = ph ? 1 - a : -a;
        const int dw = pw ? 1 - b : -b;
        const int base = ((dh + 1) * PC + (dw + 1)) * CIP + ci0;

        bf16x8 bfr[4];
        #pragma unroll
        for (int nf = 0; nf < 4; ++nf)
            bfr[nf] = *reinterpret_cast<const bf16x8*>(
                wc + (nf * 16 + (l & 15)) * 512 + ks * 32 + ((l >> 4) * 8));

        #pragma unroll
        for (int mf = 0; mf < 8; ++mf) {
            bf16x8 afr = *reinterpret_cast<const bf16x8*>(&sP[base + aoff[mf]]);
            #pragma unroll
            for (int nf = 0; nf < 4; ++nf)
                acc[mf][nf] = __builtin_amdgcn_mfma_f32_16x16x32_bf16(
                    afr, bfr[nf], acc[mf][nf], 0, 0, 0);
        }
    }

    #pragma unroll
    for (int mf = 0; mf < 8; ++mf) {
        #pragma unroll
        for (int nf = 0; nf < 4; ++nf) {
            const int col = nf * 16 + (l & 15);
            const float bv = bias[col];
            #pragma unroll
            for (int r = 0; r < 4; ++r) {
                const int prow = mf * 16 + ((l >> 4) * 4) + r;
                const int orow = 2 * R + (prow >> 6);
                const int ocol = prow & 63;
                const long long oidx =
                    (((long long)(n * 128 + 2 * orow + ph)) * 128 + 2 * ocol + pw) * 64 + col;
                float v = fmaxf(acc[mf][nf][r] + bv, 0.f);
                out[oidx] = f2bf(v);
            }
        }
    }
}

// ---------------------------------------------------------------------------
// conv2 (4x4 s2, 128x128 -> 64x64): keep v2 gather structure.
// ---------------------------------------------------------------------------
template<int CIN, int COUT, bool RELU_OUT>
__global__ __launch_bounds__(256)
void conv_s2(const ushort* __restrict__ in, const ushort* __restrict__ wt,
             const float* __restrict__ bias, ushort* __restrict__ out,
             int Hin, int Win) {
    constexpr int K = 16 * CIN;
    constexpr int KSTEPS = K / 32;
    constexpr int CSTEPS = CIN / 32;
    constexpr int WM = 4, WN = 4;

    __shared__ ushort sA[2][128 * 40];

    const int t = threadIdx.x;
    const int w = t >> 6, l = t & 63;
    const int bid = blockIdx.x;
    const int n = bid >> 5, R = bid & 31;

    const int m0 = 64 * (w >> 1);
    const int n0 = 64 * (w & 1);

    const int gpx  = t >> 1;
    const int gk   = (t & 1) * 16;
    const int grow = 2 * R + (gpx >> 6);
    const int gcol = gpx & 63;

    auto gather = [&](int ks, uint4& g0, uint4& g1) {
        int tap, ci0;
        if (CSTEPS == 1) { tap = ks; ci0 = 0; }
        else             { tap = ks / CSTEPS; ci0 = (ks % CSTEPS) * 32; }
        const int dh = tap / 4 - 1, dw = tap % 4 - 1;
        const int ih = 2 * grow + dh, iw = 2 * gcol + dw;
        g0 = make_uint4(0u, 0u, 0u, 0u); g1 = g0;
        if ((unsigned)ih < (unsigned)Hin && (unsigned)iw < (unsigned)Win) {
            const ushort* p = in + (((long long)(n * Hin + ih)) * Win + iw) * CIN + ci0 + gk;
            g0 = *reinterpret_cast<const uint4*>(p);
            g1 = *reinterpret_cast<const uint4*>(p + 8);
        }
    };

    f32x4 acc[WM][WN] = {};

    uint4 g0, g1;
    gather(0, g0, g1);
    *reinterpret_cast<uint4*>(&sA[0][gpx * 40 + gk])     = g0;
    *reinterpret_cast<uint4*>(&sA[0][gpx * 40 + gk + 8]) = g1;
    __syncthreads();

    int cur = 0;
    for (int ks = 0; ks < KSTEPS; ++ks) {
        const bool more = (ks + 1 < KSTEPS);
        uint4 h0, h1;
        if (more) gather(ks + 1, h0, h1);

        bf16x8 bfr[WN];
        #pragma unroll
        for (int nf = 0; nf < WN; ++nf)
            bfr[nf] = *reinterpret_cast<const bf16x8*>(
                wt + (n0 + nf * 16 + (l & 15)) * K + ks * 32 + ((l >> 4) * 8));

        bf16x8 afr[WM];
        #pragma unroll
        for (int mf = 0; mf < WM; ++mf)
            afr[mf] = *reinterpret_cast<const bf16x8*>(
                &sA[cur][(m0 + mf * 16 + (l & 15)) * 40 + ((l >> 4) * 8)]);

        #pragma unroll
        for (int mf = 0; mf < WM; ++mf)
            #pragma unroll
            for (int nf = 0; nf < WN; ++nf)
                acc[mf][nf] = __builtin_amdgcn_mfma_f32_16x16x32_bf16(
                    afr[mf], bfr[nf], acc[mf][nf], 0, 0, 0);

        if (more) {
            *reinterpret_cast<uint4*>(&sA[cur ^ 1][gpx * 40 + gk])     = h0;
            *reinterpret_cast<uint4*>(&sA[cur ^ 1][gpx * 40 + gk + 8]) = h1;
            __syncthreads();
            cur ^= 1;
        }
    }

    #pragma unroll
    for (int mf = 0; mf < WM; ++mf) {
        #pragma unroll
        for (int nf = 0; nf < WN; ++nf) {
            const int col = n0 + nf * 16 + (l & 15);
            const float bv = bias[col];
            #pragma unroll
            for (int r = 0; r < 4; ++r) {
                const int prow = m0 + mf * 16 + ((l >> 4) * 4) + r;
                const int orow = 2 * R + (prow >> 6);
                const int ocol = prow & 63;
                const long long oidx = (((long long)(n * 64 + orow)) * 64 + ocol) * COUT + col;
                float v = acc[mf][nf][r] + bv;
                if (RELU_OUT) v = fmaxf(v, 0.f);
                out[oidx] = f2bf(v);
            }
        }
    }
}

// ---------------------------------------------------------------------------
// conv1: 3->64, 4x4 s2 pad1, fp32 NCHW in -> bf16 NHWC out, relu.
// sW padded [co][49]: write = consecutive addrs (conflict-free);
// read at fixed k across lanes co: bank=(17*co+k)%32 -> 2 lanes/bank (free).
// ---------------------------------------------------------------------------
__global__ __launch_bounds__(256)
void conv1_k(const float* __restrict__ x, const float* __restrict__ w1,
             const float* __restrict__ b1, ushort* __restrict__ out) {
    __shared__ float sIn[3 * 4 * 36];
    __shared__ float sW[64 * 49];           // [co][k], stride 49 (odd => bank-spread)
    const int t = threadIdx.x;
    const int bid = blockIdx.x;
    const int n = bid >> 7, oh = bid & 127;
    const int ow0 = blockIdx.y * 16;

    for (int i = t; i < 3072; i += 256) {
        int co = i / 48, k = i % 48;
        sW[co * 49 + k] = w1[i];
    }
    for (int i = t; i < 3 * 4 * 34; i += 256) {
        int ci = i / 136, r = i - ci * 136;
        int r4 = r / 34, iwl = r % 34;
        int ih = 2 * oh - 1 + r4;
        int iw = 2 * ow0 - 1 + iwl;
        float v = 0.f;
        if ((unsigned)ih < 256u && (unsigned)iw < 256u)
            v = x[((n * 3 + ci) * 256 + ih) * 256 + iw];
        sIn[ci * 144 + r4 * 36 + iwl] = v;
    }
    __syncthreads();

    const int co = t & 63, j = t >> 6;
    float wr[48];
    #pragma unroll
    for (int i = 0; i < 48; ++i) wr[i] = sW[co * 49 + i];
    const float bv = b1[co];

    #pragma unroll
    for (int q = 0; q < 4; ++q) {
        const int owl = j * 4 + q;
        float acc = bv;
        #pragma unroll
        for (int ci = 0; ci < 3; ++ci)
            #pragma unroll
            for (int kh = 0; kh < 4; ++kh)
                #pragma unroll
                for (int kw = 0; kw < 4; ++kw)
                    acc = fmaf(sIn[ci * 144 + kh * 36 + 2 * owl + kw],
                               wr[ci * 16 + kh * 4 + kw], acc);
        acc = fmaxf(acc, 0.f);
        out[(((long long)(n * 128 + oh)) * 128 + ow0 + owl) * 64 + co] = f2bf(acc);
    }
}

// ---------------------------------------------------------------------------
// convT2: 64->3, k4 s2 p1, bf16 NHWC in [32,128,128,64] -> fp32 NCHW out.
// ---------------------------------------------------------------------------
__global__ __launch_bounds__(256)
void convt2_k(const ushort* __restrict__ in, const float* __restrict__ tw2,
              const float* __restrict__ tb2, float* __restrict__ out) {
    __shared__ float sW[64 * 48];           // [ci][co][16]
    const int t = threadIdx.x;
    for (int i = t; i < 3072; i += 256) sW[i] = tw2[i];
    __syncthreads();

    const int bid = blockIdx.x;
    const int n = bid >> 8, oh = bid & 255;
    const int ow = t;
    const int khA = (oh + 1) & 1, ihA = (oh + 1) >> 1;
    const int kwA = (ow + 1) & 1, iwA = (ow + 1) >> 1;

    float a0 = tb2[0], a1 = tb2[1], a2 = tb2[2];
    #pragma unroll
    for (int a = 0; a < 2; ++a) {
        const int ih = ihA - a;
        if ((unsigned)ih >= 128u) continue;
        const int kh = khA + 2 * a;
        #pragma unroll
        for (int b = 0; b < 2; ++b) {
            const int iw = iwA - b;
            if ((unsigned)iw >= 128u) continue;
            const int kw = kwA + 2 * b;
            const ushort* src = in + (((long long)(n * 128 + ih)) * 128 + iw) * 64;
            const int k = kh * 4 + kw;
            #pragma unroll
            for (int c8 = 0; c8 < 8; ++c8) {
                uint4 v = *reinterpret_cast<const uint4*>(src + c8 * 8);
                const uint u[4] = {v.x, v.y, v.z, v.w};
                #pragma unroll
                for (int p = 0; p < 4; ++p) {
                    union { uint i; float f; } lo, hi;
                    lo.i = u[p] << 16; hi.i = u[p] & 0xFFFF0000u;
                    const int ci = c8 * 8 + p * 2;
                    a0 = fmaf(lo.f, sW[ci * 48 + 0 * 16 + k], a0);
                    a1 = fmaf(lo.f, sW[ci * 48 + 1 * 16 + k], a1);
                    a2 = fmaf(lo.f, sW[ci * 48 + 2 * 16 + k], a2);
                    a0 = fmaf(hi.f, sW[(ci + 1) * 48 + 0 * 16 + k], a0);
                    a1 = fmaf(hi.f, sW[(ci + 1) * 48 + 1 * 16 + k], a1);
                    a2 = fmaf(hi.f, sW[(ci + 1) * 48 + 2 * 16 + k], a2);
                }
            }
        }
    }
    const long long px = (long long)oh * 256 + ow;
    out[(long long)(n * 3 + 0) * 65536 + px] = a0;
    out[(long long)(n * 3 + 1) * 65536 + px] = a1;
    out[(long long)(n * 3 + 2) * 65536 + px] = a2;
}

// ---------------------------------------------------------------------------
// MFMA VQ (unchanged).
// ---------------------------------------------------------------------------
__global__ __launch_bounds__(256)
void vq_mfma(const ushort* __restrict__ z, const ushort* __restrict__ Ebf,
             const float* __restrict__ E, const float* __restrict__ eN,
             ushort* __restrict__ zq, float* __restrict__ stats) {
    __shared__ ushort sZ[64 * 72];
    __shared__ float sEN[512];
    __shared__ float sV[64 * 4];
    __shared__ int   sI[64 * 4];
    __shared__ int   sIdx[64];
    __shared__ unsigned shist[512];
    __shared__ float red[256];

    const int t = threadIdx.x;
    const int w = t >> 6, l = t & 63;
    const long long p0 = (long long)blockIdx.x * 64;

    {
        const int px = t >> 2, koff = (t & 3) * 16;
        const ushort* p = z + (p0 + px) * 64 + koff;
        uint4 a0 = *reinterpret_cast<const uint4*>(p);
        uint4 a1 = *reinterpret_cast<const uint4*>(p + 8);
        *reinterpret_cast<uint4*>(&sZ[px * 72 + koff])     = a0;
        *reinterpret_cast<uint4*>(&sZ[px * 72 + koff + 8]) = a1;
        sEN[t] = eN[t]; sEN[t + 256] = eN[t + 256];
        shist[t] = 0u; shist[t + 256] = 0u;
    }
    __syncthreads();

    f32x4 acc[4][8] = {};
    #pragma unroll
    for (int ks = 0; ks < 2; ++ks) {
        bf16x8 bfr[8];
        #pragma unroll
        for (int nf = 0; nf < 8; ++nf)
            bfr[nf] = *reinterpret_cast<const bf16x8*>(
                Ebf + (w * 128 + nf * 16 + (l & 15)) * 64 + ks * 32 + ((l >> 4) * 8));
        #pragma unroll
        for (int mf = 0; mf < 4; ++mf) {
            bf16x8 afr = *reinterpret_cast<const bf16x8*>(
                &sZ[(mf * 16 + (l & 15)) * 72 + ks * 32 + ((l >> 4) * 8)]);
            #pragma unroll
            for (int nf = 0; nf < 8; ++nf)
                acc[mf][nf] = __builtin_amdgcn_mfma_f32_16x16x32_bf16(
                    afr, bfr[nf], acc[mf][nf], 0, 0, 0);
        }
    }

    float eNr[8];
    #pragma unroll
    for (int nf = 0; nf < 8; ++nf) eNr[nf] = sEN[w * 128 + nf * 16 + (l & 15)];

    #pragma unroll
    for (int mf = 0; mf < 4; ++mf) {
        #pragma unroll
        for (int r = 0; r < 4; ++r) {
            float best = 3.4e38f; int bidx = 0;
            #pragma unroll
            for (int nf = 0; nf < 8; ++nf) {
                float s = eNr[nf] - 2.f * acc[mf][nf][r];
                int   c = w * 128 + nf * 16 + (l & 15);
                if (s < best || (s == best && c < bidx)) { best = s; bidx = c; }
            }
            #pragma unroll
            for (int off = 1; off < 16; off <<= 1) {
                float ov = __shfl_xor(best, off);
                int   oi = __shfl_xor(bidx, off);
                if (ov < best || (ov == best && oi < bidx)) { best = ov; bidx = oi; }
            }
            if ((l & 15) == 0) {
                const int px = mf * 16 + ((l >> 4) * 4) + r;
                sV[px * 4 + w] = best; sI[px * 4 + w] = bidx;
            }
        }
    }
    __syncthreads();

    if (t < 64) {
        float best = sV[t * 4]; int bidx = sI[t * 4];
        #pragma unroll
        for (int w2 = 1; w2 < 4; ++w2) {
            float v = sV[t * 4 + w2]; int c = sI[t * 4 + w2];
            if (v < best || (v == best && c < bidx)) { best = v; bidx = c; }
        }
        sIdx[t] = bidx;
        atomicAdd(&shist[bidx], 1u);
    }
    __syncthreads();

    {
        const int px = t >> 2, doff = (t & 3) * 16;
        const int idx = sIdx[px];
        const float* e = E + idx * 64 + doff;
        float dist = 0.f;
        uint4 pk4[2];
        ushort* pk = reinterpret_cast<ushort*>(pk4);
        #pragma unroll
        for (int j = 0; j < 16; ++j) {
            float ev = e[j];
            float zv = bf2f(sZ[px * 72 + doff + j]);
            float df = ev - zv;
            dist = fmaf(df, df, dist);
            pk[j] = f2bf(ev);
        }
        *reinterpret_cast<uint4*>(zq + (p0 + px) * 64 + doff)     = pk4[0];
        *reinterpret_cast<uint4*>(zq + (p0 + px) * 64 + doff + 8) = pk4[1];
        red[t] = dist;
    }
    __syncthreads();
    for (int s = 128; s > 0; s >>= 1) {
        if (t < s) red[t] += red[t + s];
        __syncthreads();
    }
    if (t == 0) atomicAdd(&stats[0], red[0]);
    for (int i = t; i < 512; i += 256) {
        unsigned c = shist[i];
        if (c) atomicAdd(&stats[1 + i], (float)c);
    }
}

__global__ __launch_bounds__(512)
void finalize_kernel(const float* __restrict__ stats, float* __restrict__ out, int plast) {
    __shared__ float red[512];
    int t = threadIdx.x;
    float c = stats[1 + t];
    float p = c * (1.f / 131072.f);
    red[t] = p * logf(p + 1e-10f);
    __syncthreads();
    for (int s = 256; s > 0; s >>= 1) {
        if (t < s) red[t] += red[t + s];
        __syncthreads();
    }
    if (t == 0) {
        out[plast] = expf(-red[0]);
        out[0] = 7.6f * stats[0] * (1.f / 8388608.f);
    }
}

// ---------------------------------------------------------------------------
extern "C" void kernel_launch(void* const* d_in, const int* in_sizes, int n_in,
                              void* d_out, int out_size, void* d_ws, size_t ws_size,
                              hipStream_t stream) {
    (void)in_sizes; (void)n_in; (void)ws_size;
    const float* x   = (const float*)d_in[0];
    const float* w1  = (const float*)d_in[1];
    const float* b1  = (const float*)d_in[2];
    const float* w2  = (const float*)d_in[3];
    const float* b2  = (const float*)d_in[4];
    const float* w3  = (const float*)d_in[5];
    const float* b3  = (const float*)d_in[6];
    const float* r0a = (const float*)d_in[7];
    const float* r0b = (const float*)d_in[8];
    const float* r1a = (const float*)d_in[9];
    const float* r1b = (const float*)d_in[10];
    const float* wp  = (const float*)d_in[11];
    const float* bp  = (const float*)d_in[12];
    const float* E   = (const float*)d_in[13];
    const float* dw1 = (const float*)d_in[14];
    const float* db1 = (const float*)d_in[15];
    const float* dr0a= (const float*)d_in[16];
    const float* dr0b= (const float*)d_in[17];
    const float* dr1a= (const float*)d_in[18];
    const float* dr1b= (const float*)d_in[19];
    const float* tw1 = (const float*)d_in[20];
    const float* tb1 = (const float*)d_in[21];
    const float* tw2 = (const float*)d_in[22];
    const float* tb2 = (const float*)d_in[23];

    float* out = (float*)d_out;
    ushort* ws = (ushort*)d_ws;

    ushort* H1 = ws;                  // [32,128,128,64] ; later convT1 out T
    ushort* H2 = ws + 33554432;       // [32,64,64,128]  ; later decoder D
    ushort* C  = ws + 50331648;       // [32,64,64,128]
    ushort* F  = ws + 67108864;       // [32,64,64,32]  res temp
    ushort* Z  = ws + 71303168;       // [131072,64]
    ushort* ZQ = ws + 79691776;       // [131072,64]
    ushort* W0 = ws + 88080384;       // weight block
    ushort* Wt2   = W0;               // 131072
    ushort* Wt3   = W0 + 131072;      // 147456
    ushort* Wr0a  = W0 + 278528;
    ushort* Wr0b  = W0 + 315392;
    ushort* Wr1a  = W0 + 352256;
    ushort* Wr1b  = W0 + 389120;
    ushort* Wp    = W0 + 425984;
    ushort* Wd1   = W0 + 434176;
    ushort* Wdr0a = W0 + 507904;
    ushort* Wdr0b = W0 + 544768;
    ushort* Wdr1a = W0 + 581632;
    ushort* Wdr1b = W0 + 618496;
    ushort* WT1   = W0 + 655360;      // 131072 -> ends W0+786432
    ushort* Ebf   = W0 + 786432;      // 32768
    float*  eN    = (float*)(W0 + 819200);   // 512 floats
    float*  ST    = (float*)(W0 + 820224);   // 513 floats
    ushort* T = H1;
    ushort* D = H2;

    hipMemsetAsync(ST, 0, 513 * sizeof(float), stream);

    dim3 blk(256);
    wt_oihw<64, 128,16><<<512, blk, 0, stream>>>(w2,  Wt2);
    wt_oihw<128,128, 9><<<576, blk, 0, stream>>>(w3,  Wt3);
    wt_oihw<128, 32, 9><<<144, blk, 0, stream>>>(r0a, Wr0a);
    wt_oihw<32, 128, 9><<<144, blk, 0, stream>>>(r0b, Wr0b);
    wt_oihw<128, 32, 9><<<144, blk, 0, stream>>>(r1a, Wr1a);
    wt_oihw<32, 128, 9><<<144, blk, 0, stream>>>(r1b, Wr1b);
    wt_oihw<128, 64, 1><<<32,  blk, 0, stream>>>(wp,  Wp);
    wt_oihw<64, 128, 9><<<288, blk, 0, stream>>>(dw1, Wd1);
    wt_oihw<128, 32, 9><<<144, blk, 0, stream>>>(dr0a, Wdr0a);
    wt_oihw<32, 128, 9><<<144, blk, 0, stream>>>(dr0b, Wdr0b);
    wt_oihw<128, 32, 9><<<144, blk, 0, stream>>>(dr1a, Wdr1a);
    wt_oihw<32, 128, 9><<<144, blk, 0, stream>>>(dr1b, Wdr1b);
    wt_tconv1<<<512, blk, 0, stream>>>(tw1, WT1);
    vq_prep<<<128, blk, 0, stream>>>(E, Ebf, eN);

    // ---- encoder ----
    conv1_k<<<dim3(32 * 128, 8), blk, 0, stream>>>(x, w1, b1, H1);
    conv_s2<64,128,true><<<1024, blk, 0, stream>>>(H1, Wt2, b2, H2, 128, 128);
    conv_lds<128,128,9,1,false,false,false><<<1024, blk, 0, stream>>>(H2, Wt3, b3, nullptr, C);
    conv_lds<128, 32,9,1,true ,true ,false><<<1024, blk, 0, stream>>>(C, Wr0a, nullptr, nullptr, F);
    conv_lds<32, 128,9,1,false,false,true ><<<1024, blk, 0, stream>>>(F, Wr0b, nullptr, C, C);
    conv_lds<128, 32,9,1,true ,true ,false><<<1024, blk, 0, stream>>>(C, Wr1a, nullptr, nullptr, F);
    conv_lds<32, 128,9,1,false,true ,true ><<<1024, blk, 0, stream>>>(F, Wr1b, nullptr, C, C);
    conv_lds<128, 64,1,0,false,false,false><<<1024, blk, 0, stream>>>(C, Wp, bp, nullptr, Z);

    // ---- VQ ----
    vq_mfma<<<2048, blk, 0, stream>>>(Z, Ebf, E, eN, ZQ, ST);

    // ---- decoder ----
    conv_lds<64, 128,9,1,false,false,false><<<1024, blk, 0, stream>>>(ZQ, Wd1, db1, nullptr, D);
    conv_lds<128, 32,9,1,true ,true ,false><<<1024, blk, 0, stream>>>(D, Wdr0a, nullptr, nullptr, F);
    conv_lds<32, 128,9,1,false,false,true ><<<1024, blk, 0, stream>>>(F, Wdr0b, nullptr, D, D);
    conv_lds<128, 32,9,1,true ,true ,false><<<1024, blk, 0, stream>>>(D, Wdr1a, nullptr, nullptr, F);
    conv_lds<32, 128,9,1,false,true ,true ><<<1024, blk, 0, stream>>>(F, Wdr1b, nullptr, D, D);
    convt1_lds<<<1024, blk, 0, stream>>>(D, WT1, tb1, T);
    convt2_k<<<32 * 256, blk, 0, stream>>>(T, tw2, tb2, out + 1);

    // ---- loss / perplexity ----
    finalize_kernel<<<1, 512, 0, stream>>>(ST, out, out_size - 1);
}

// Round 10
// 1103.253 us; speedup vs baseline: 30.6782x; 1.1164x over previous
//
#include <hip/hip_runtime.h>
#include <math.h>

typedef __attribute__((ext_vector_type(8))) short bf16x8;
typedef __attribute__((ext_vector_type(4))) float f32x4;

__device__ inline float bf2f(ushort u) {
    union { uint i; float f; } v; v.i = ((uint)u) << 16; return v.f;
}
__device__ inline ushort f2bf(float f) {
    union { float f; uint i; } v; v.f = f;
    uint b = v.i;
    b += 0x7FFFu + ((b >> 16) & 1u);      // RNE
    return (ushort)(b >> 16);
}
__device__ inline uint relu2bf(uint x) {
    uint s = x & 0x80008000u;
    uint m = (s >> 15) * 0xFFFFu;
    return x & ~m;
}

// ---------------------------------------------------------------------------
// Merged prep kernel: all weight transforms + VQ prep + conv1 weights, ONE
// launch (was 15). Segment dispatch by blockIdx range.
// wt_oihw body: bf16 [co][tap*CIN+ci]
// ---------------------------------------------------------------------------
template<int CIN, int COUT, int NT>
__device__ inline void wt_body(int i, const float* __restrict__ s, ushort* __restrict__ d) {
    if (i >= COUT * NT * CIN) return;
    int co = i / (NT * CIN);
    int r  = i % (NT * CIN);
    int tap = r / CIN, ci = r % CIN;
    d[i] = f2bf(s[(co * CIN + ci) * NT + tap]);
}

__global__ __launch_bounds__(256)
void wt_all(const float* w2, ushort* Wt2, const float* w3, ushort* Wt3,
            const float* r0a, ushort* Wr0a, const float* r0b, ushort* Wr0b,
            const float* r1a, ushort* Wr1a, const float* r1b, ushort* Wr1b,
            const float* wp,  ushort* Wp,   const float* dw1, ushort* Wd1,
            const float* dr0a, ushort* Wdr0a, const float* dr0b, ushort* Wdr0b,
            const float* dr1a, ushort* Wdr1a, const float* dr1b, ushort* Wdr1b,
            const float* tw1, ushort* WT1,
            const float* E, ushort* Ebf, float* eN,
            const float* w1, ushort* Wc1) {
    const int b = blockIdx.x, t = threadIdx.x;
    if (b < 512)        { wt_body<64, 128,16>(b * 256 + t, w2,  Wt2); }
    else if (b < 1088)  { wt_body<128,128, 9>((b-512) * 256 + t, w3, Wt3); }
    else if (b < 1232)  { wt_body<128, 32, 9>((b-1088) * 256 + t, r0a, Wr0a); }
    else if (b < 1376)  { wt_body<32, 128, 9>((b-1232) * 256 + t, r0b, Wr0b); }
    else if (b < 1520)  { wt_body<128, 32, 9>((b-1376) * 256 + t, r1a, Wr1a); }
    else if (b < 1664)  { wt_body<32, 128, 9>((b-1520) * 256 + t, r1b, Wr1b); }
    else if (b < 1696)  { wt_body<128, 64, 1>((b-1664) * 256 + t, wp,  Wp); }
    else if (b < 1984)  { wt_body<64, 128, 9>((b-1696) * 256 + t, dw1, Wd1); }
    else if (b < 2128)  { wt_body<128, 32, 9>((b-1984) * 256 + t, dr0a, Wdr0a); }
    else if (b < 2272)  { wt_body<32, 128, 9>((b-2128) * 256 + t, dr0b, Wdr0b); }
    else if (b < 2416)  { wt_body<128, 32, 9>((b-2272) * 256 + t, dr1a, Wdr1a); }
    else if (b < 2560)  { wt_body<32, 128, 9>((b-2416) * 256 + t, dr1b, Wdr1b); }
    else if (b < 3072) {
        // convT1 tw1 [128ci][64co][4][4] -> 4 classes [cls][64co][4tap*128ci]
        int i = (b - 2560) * 256 + t;
        if (i < 4 * 64 * 512) {
            int cls = i >> 15;
            int co  = (i >> 9) & 63;
            int k   = i & 511;
            int tap = k >> 7, ci = k & 127;
            int a = tap >> 1, bb = tap & 1;
            int ph = cls >> 1, pw = cls & 1;
            int kh = ph ? (a ? 2 : 0) : (a ? 3 : 1);
            int kw = pw ? (bb ? 2 : 0) : (bb ? 3 : 1);
            WT1[i] = f2bf(tw1[((ci * 64 + co) << 4) + kh * 4 + kw]);
        }
    } else if (b < 3200) {
        int i = (b - 3072) * 256 + t;
        if (i < 32768) Ebf[i] = f2bf(E[i]);
        if (i < 512) {
            float s = 0.f;
            #pragma unroll 8
            for (int d = 0; d < 64; ++d) { float xx = E[i * 64 + d]; s = fmaf(xx, xx, s); }
            eN[i] = s;
        }
    } else {
        // conv1 weights: w1 [64co][3ci][4][4] -> [64co][64k], k=ci*16+kh*4+kw, pad 48..63=0
        int i = (b - 3200) * 256 + t;
        if (i < 4096) {
            int co = i >> 6, k = i & 63;
            Wc1[i] = (k < 48) ? f2bf(w1[co * 48 + k]) : (ushort)0;
        }
    }
}

// ---------------------------------------------------------------------------
// conv1 MFMA: 3->64, 4x4 s2 pad1, fp32 NCHW in -> bf16 NHWC out, relu.
// GEMM M=524288 px, K=48 (pad 64), N=64. Block = one output row (128 px).
// Stage raw rows fp32 -> LDS, build im2col A-tile bf16 -> LDS, 16 MFMA/wave.
// ---------------------------------------------------------------------------
__global__ __launch_bounds__(256)
void conv1_mfma(const float* __restrict__ x, const ushort* __restrict__ wt,
                const float* __restrict__ b1, ushort* __restrict__ out) {
    __shared__ float  sIn[3 * 4 * 264];     // [ci][4 rows][258 cols + pad]
    __shared__ ushort sA[128 * 72];         // [px][64 k + pad]

    const int t = threadIdx.x;
    const int w = t >> 6, l = t & 63;
    const int bid = blockIdx.x;
    const int n = bid >> 7, oh = bid & 127;

    // stage 4 input rows x 258 cols x 3 ci (iw = -1..256)
    for (int i = t; i < 3 * 4 * 258; i += 256) {
        const int ci = i / 1032, rem = i % 1032;
        const int r4 = rem / 258, c = rem % 258;
        const int ih = 2 * oh - 1 + r4, iw = c - 1;
        float v = 0.f;
        if ((unsigned)ih < 256u && (unsigned)iw < 256u)
            v = x[((n * 3 + ci) * 256 + ih) * 256 + iw];
        sIn[(ci * 4 + r4) * 264 + c] = v;
    }
    __syncthreads();

    // build A: px 0..127, k = ci*16+kh*4+kw (48 real, pad to 64)
    for (int i = t; i < 128 * 6; i += 256) {
        const int px = i / 6, seg = i % 6, k0 = seg * 8;
        ushort pk[8];
        #pragma unroll
        for (int j = 0; j < 8; ++j) {
            const int k = k0 + j;
            float v = 0.f;
            if (k < 48) {
                const int ci = k >> 4, kh = (k >> 2) & 3, kw = k & 3;
                v = sIn[(ci * 4 + kh) * 264 + 2 * px + kw];
            }
            pk[j] = f2bf(v);
        }
        *reinterpret_cast<uint4*>(&sA[px * 72 + k0]) =
            *reinterpret_cast<const uint4*>(pk);
    }
    __syncthreads();

    const int m0 = 32 * w;                  // wave w: px 32w..32w+31
    f32x4 acc[2][4] = {};
    #pragma unroll
    for (int ks = 0; ks < 2; ++ks) {
        bf16x8 bfr[4];
        #pragma unroll
        for (int nf = 0; nf < 4; ++nf)
            bfr[nf] = *reinterpret_cast<const bf16x8*>(
                wt + (nf * 16 + (l & 15)) * 64 + ks * 32 + ((l >> 4) * 8));
        #pragma unroll
        for (int mf = 0; mf < 2; ++mf) {
            bf16x8 afr = *reinterpret_cast<const bf16x8*>(
                &sA[(m0 + mf * 16 + (l & 15)) * 72 + ks * 32 + ((l >> 4) * 8)]);
            #pragma unroll
            for (int nf = 0; nf < 4; ++nf)
                acc[mf][nf] = __builtin_amdgcn_mfma_f32_16x16x32_bf16(
                    afr, bfr[nf], acc[mf][nf], 0, 0, 0);
        }
    }

    #pragma unroll
    for (int mf = 0; mf < 2; ++mf) {
        #pragma unroll
        for (int nf = 0; nf < 4; ++nf) {
            const int col = nf * 16 + (l & 15);
            const float bv = b1[col];
            #pragma unroll
            for (int r = 0; r < 4; ++r) {
                const int ow = m0 + mf * 16 + ((l >> 4) * 4) + r;
                float v = fmaxf(acc[mf][nf][r] + bv, 0.f);
                out[(((long long)(n * 128 + oh)) * 128 + ow) * 64 + col] = f2bf(v);
            }
        }
    }
}

// ---------------------------------------------------------------------------
// Stage-once LDS-patch MFMA conv for 64x64 maps (unchanged from round 9).
// ---------------------------------------------------------------------------
template<int CIN, int COUT, int NT, int HALO, bool RELU_A, bool RELU_OUT, bool HAS_RES>
__global__ __launch_bounds__(256)
void conv_lds(const ushort* __restrict__ in, const ushort* __restrict__ wt,
              const float* __restrict__ bias, const ushort* __restrict__ res,
              ushort* __restrict__ out) {
    constexpr int K = NT * CIN;
    constexpr int KSTEPS = K / 32;
    constexpr int CSTEPS = CIN / 32;
    constexpr int PR = HALO ? 4 : 2;
    constexpr int PC = HALO ? 66 : 64;
    constexpr int CIP = CIN + 8;
    constexpr int WM = (COUT == 128) ? 4 : 2;
    constexpr int WN = (COUT == 32) ? 2 : 4;
    constexpr int NC8 = CIN / 8;
    constexpr int NLD = PR * PC * NC8;

    __shared__ ushort sP[PR * PC * CIP];

    const int t = threadIdx.x;
    const int w = t >> 6, l = t & 63;
    const int bid = blockIdx.x;
    const int n = bid >> 5, R = bid & 31;

    const int m0 = (COUT == 128) ? 64 * (w >> 1) : 32 * w;
    const int n0 = (COUT == 128) ? 64 * (w & 1) : 0;

    for (int i = t; i < NLD; i += 256) {
        const int c8  = i & (NC8 - 1);
        const int rem = i / NC8;
        const int pc  = rem % PC;
        const int pr  = rem / PC;
        const int grow = 2 * R - HALO + pr;
        const int gcol = pc - HALO;
        uint4 v = make_uint4(0u, 0u, 0u, 0u);
        if (!HALO || ((unsigned)grow < 64u && (unsigned)gcol < 64u))
            v = *reinterpret_cast<const uint4*>(
                in + (((long long)(n * 64 + grow)) * 64 + gcol) * CIN + c8 * 8);
        if (RELU_A) {
            v.x = relu2bf(v.x); v.y = relu2bf(v.y);
            v.z = relu2bf(v.z); v.w = relu2bf(v.w);
        }
        *reinterpret_cast<uint4*>(&sP[(pr * PC + pc) * CIP + c8 * 8]) = v;
    }
    __syncthreads();

    int aoff[WM];
    #pragma unroll
    for (int mf = 0; mf < WM; ++mf) {
        const int px = m0 + mf * 16 + (l & 15);
        aoff[mf] = ((px >> 6) * PC + (px & 63)) * CIP + ((l >> 4) * 8);
    }

    f32x4 acc[WM][WN] = {};

    for (int ks = 0; ks < KSTEPS; ++ks) {
        const int tap = (CSTEPS == 1) ? ks : ks / CSTEPS;
        const int ci0 = (CSTEPS == 1) ? 0 : (ks % CSTEPS) * 32;
        int dh = 0, dw = 0;
        if (NT == 9) { dh = tap / 3 - 1; dw = tap % 3 - 1; }
        const int base = ((dh + HALO) * PC + (dw + HALO)) * CIP + ci0;

        bf16x8 bfr[WN];
        #pragma unroll
        for (int nf = 0; nf < WN; ++nf)
            bfr[nf] = *reinterpret_cast<const bf16x8*>(
                wt + (n0 + nf * 16 + (l & 15)) * K + ks * 32 + ((l >> 4) * 8));

        #pragma unroll
        for (int mf = 0; mf < WM; ++mf) {
            bf16x8 afr = *reinterpret_cast<const bf16x8*>(&sP[base + aoff[mf]]);
            #pragma unroll
            for (int nf = 0; nf < WN; ++nf)
                acc[mf][nf] = __builtin_amdgcn_mfma_f32_16x16x32_bf16(
                    afr, bfr[nf], acc[mf][nf], 0, 0, 0);
        }
    }

    #pragma unroll
    for (int mf = 0; mf < WM; ++mf) {
        #pragma unroll
        for (int nf = 0; nf < WN; ++nf) {
            const int col = n0 + nf * 16 + (l & 15);
            const float bv = bias ? bias[col] : 0.f;
            #pragma unroll
            for (int r = 0; r < 4; ++r) {
                const int prow = m0 + mf * 16 + ((l >> 4) * 4) + r;
                const int orow = 2 * R + (prow >> 6);
                const int ocol = prow & 63;
                const long long oidx = (((long long)(n * 64 + orow)) * 64 + ocol) * COUT + col;
                float v = acc[mf][nf][r] + bv;
                if (HAS_RES) v += bf2f(res[oidx]);
                if (RELU_OUT) v = fmaxf(v, 0.f);
                out[oidx] = f2bf(v);
            }
        }
    }
}

// ---------------------------------------------------------------------------
// convT1 merged (unchanged from round 9).
// ---------------------------------------------------------------------------
__global__ __launch_bounds__(256)
void convt1_lds(const ushort* __restrict__ in, const ushort* __restrict__ wt,
                const float* __restrict__ bias, ushort* __restrict__ out) {
    constexpr int CIN = 128, CIP = 136, PC = 66;
    __shared__ ushort sP[4 * PC * CIP];

    const int t = threadIdx.x;
    const int w = t >> 6, l = t & 63;
    const int bid = blockIdx.x;
    const int n = bid >> 5, R = bid & 31;

    for (int i = t; i < 4 * PC * 16; i += 256) {
        const int c8  = i & 15;
        const int rem = i >> 4;
        const int pc  = rem % PC;
        const int pr  = rem / PC;
        const int grow = 2 * R - 1 + pr;
        const int gcol = pc - 1;
        uint4 v = make_uint4(0u, 0u, 0u, 0u);
        if ((unsigned)grow < 64u && (unsigned)gcol < 64u)
            v = *reinterpret_cast<const uint4*>(
                in + (((long long)(n * 64 + grow)) * 64 + gcol) * CIN + c8 * 8);
        *reinterpret_cast<uint4*>(&sP[(pr * PC + pc) * CIP + c8 * 8]) = v;
    }
    __syncthreads();

    const int ph = w >> 1, pw = w & 1;
    const ushort* wc = wt + w * 32768;

    int aoff[8];
    #pragma unroll
    for (int mf = 0; mf < 8; ++mf) {
        const int px = mf * 16 + (l & 15);
        aoff[mf] = ((px >> 6) * PC + (px & 63)) * CIP + ((l >> 4) * 8);
    }

    f32x4 acc[8][4] = {};

    for (int ks = 0; ks < 16; ++ks) {
        const int tap = ks >> 2, ci0 = (ks & 3) * 32;
        const int a = tap >> 1, b = tap & 1;
        const int dh = ph ? 1 - a : -a;
        const int dw = pw ? 1 - b : -b;
        const int base = ((dh + 1) * PC + (dw + 1)) * CIP + ci0;

        bf16x8 bfr[4];
        #pragma unroll
        for (int nf = 0; nf < 4; ++nf)
            bfr[nf] = *reinterpret_cast<const bf16x8*>(
                wc + (nf * 16 + (l & 15)) * 512 + ks * 32 + ((l >> 4) * 8));

        #pragma unroll
        for (int mf = 0; mf < 8; ++mf) {
            bf16x8 afr = *reinterpret_cast<const bf16x8*>(&sP[base + aoff[mf]]);
            #pragma unroll
            for (int nf = 0; nf < 4; ++nf)
                acc[mf][nf] = __builtin_amdgcn_mfma_f32_16x16x32_bf16(
                    afr, bfr[nf], acc[mf][nf], 0, 0, 0);
        }
    }

    #pragma unroll
    for (int mf = 0; mf < 8; ++mf) {
        #pragma unroll
        for (int nf = 0; nf < 4; ++nf) {
            const int col = nf * 16 + (l & 15);
            const float bv = bias[col];
            #pragma unroll
            for (int r = 0; r < 4; ++r) {
                const int prow = mf * 16 + ((l >> 4) * 4) + r;
                const int orow = 2 * R + (prow >> 6);
                const int ocol = prow & 63;
                const long long oidx =
                    (((long long)(n * 128 + 2 * orow + ph)) * 128 + 2 * ocol + pw) * 64 + col;
                float v = fmaxf(acc[mf][nf][r] + bv, 0.f);
                out[oidx] = f2bf(v);
            }
        }
    }
}

// ---------------------------------------------------------------------------
// conv2 (4x4 s2, 128x128 -> 64x64): unchanged.
// ---------------------------------------------------------------------------
template<int CIN, int COUT, bool RELU_OUT>
__global__ __launch_bounds__(256)
void conv_s2(const ushort* __restrict__ in, const ushort* __restrict__ wt,
             const float* __restrict__ bias, ushort* __restrict__ out,
             int Hin, int Win) {
    constexpr int K = 16 * CIN;
    constexpr int KSTEPS = K / 32;
    constexpr int CSTEPS = CIN / 32;
    constexpr int WM = 4, WN = 4;

    __shared__ ushort sA[2][128 * 40];

    const int t = threadIdx.x;
    const int w = t >> 6, l = t & 63;
    const int bid = blockIdx.x;
    const int n = bid >> 5, R = bid & 31;

    const int m0 = 64 * (w >> 1);
    const int n0 = 64 * (w & 1);

    const int gpx  = t >> 1;
    const int gk   = (t & 1) * 16;
    const int grow = 2 * R + (gpx >> 6);
    const int gcol = gpx & 63;

    auto gather = [&](int ks, uint4& g0, uint4& g1) {
        int tap, ci0;
        if (CSTEPS == 1) { tap = ks; ci0 = 0; }
        else             { tap = ks / CSTEPS; ci0 = (ks % CSTEPS) * 32; }
        const int dh = tap / 4 - 1, dw = tap % 4 - 1;
        const int ih = 2 * grow + dh, iw = 2 * gcol + dw;
        g0 = make_uint4(0u, 0u, 0u, 0u); g1 = g0;
        if ((unsigned)ih < (unsigned)Hin && (unsigned)iw < (unsigned)Win) {
            const ushort* p = in + (((long long)(n * Hin + ih)) * Win + iw) * CIN + ci0 + gk;
            g0 = *reinterpret_cast<const uint4*>(p);
            g1 = *reinterpret_cast<const uint4*>(p + 8);
        }
    };

    f32x4 acc[WM][WN] = {};

    uint4 g0, g1;
    gather(0, g0, g1);
    *reinterpret_cast<uint4*>(&sA[0][gpx * 40 + gk])     = g0;
    *reinterpret_cast<uint4*>(&sA[0][gpx * 40 + gk + 8]) = g1;
    __syncthreads();

    int cur = 0;
    for (int ks = 0; ks < KSTEPS; ++ks) {
        const bool more = (ks + 1 < KSTEPS);
        uint4 h0, h1;
        if (more) gather(ks + 1, h0, h1);

        bf16x8 bfr[WN];
        #pragma unroll
        for (int nf = 0; nf < WN; ++nf)
            bfr[nf] = *reinterpret_cast<const bf16x8*>(
                wt + (n0 + nf * 16 + (l & 15)) * K + ks * 32 + ((l >> 4) * 8));

        bf16x8 afr[WM];
        #pragma unroll
        for (int mf = 0; mf < WM; ++mf)
            afr[mf] = *reinterpret_cast<const bf16x8*>(
                &sA[cur][(m0 + mf * 16 + (l & 15)) * 40 + ((l >> 4) * 8)]);

        #pragma unroll
        for (int mf = 0; mf < WM; ++mf)
            #pragma unroll
            for (int nf = 0; nf < WN; ++nf)
                acc[mf][nf] = __builtin_amdgcn_mfma_f32_16x16x32_bf16(
                    afr[mf], bfr[nf], acc[mf][nf], 0, 0, 0);

        if (more) {
            *reinterpret_cast<uint4*>(&sA[cur ^ 1][gpx * 40 + gk])     = h0;
            *reinterpret_cast<uint4*>(&sA[cur ^ 1][gpx * 40 + gk + 8]) = h1;
            __syncthreads();
            cur ^= 1;
        }
    }

    #pragma unroll
    for (int mf = 0; mf < WM; ++mf) {
        #pragma unroll
        for (int nf = 0; nf < WN; ++nf) {
            const int col = n0 + nf * 16 + (l & 15);
            const float bv = bias[col];
            #pragma unroll
            for (int r = 0; r < 4; ++r) {
                const int prow = m0 + mf * 16 + ((l >> 4) * 4) + r;
                const int orow = 2 * R + (prow >> 6);
                const int ocol = prow & 63;
                const long long oidx = (((long long)(n * 64 + orow)) * 64 + ocol) * COUT + col;
                float v = acc[mf][nf][r] + bv;
                if (RELU_OUT) v = fmaxf(v, 0.f);
                out[oidx] = f2bf(v);
            }
        }
    }
}

// ---------------------------------------------------------------------------
// convT2: 64->3, k4 s2 p1, bf16 NHWC in -> fp32 NCHW out (unchanged).
// ---------------------------------------------------------------------------
__global__ __launch_bounds__(256)
void convt2_k(const ushort* __restrict__ in, const float* __restrict__ tw2,
              const float* __restrict__ tb2, float* __restrict__ out) {
    __shared__ float sW[64 * 48];           // [ci][co][16]
    const int t = threadIdx.x;
    for (int i = t; i < 3072; i += 256) sW[i] = tw2[i];
    __syncthreads();

    const int bid = blockIdx.x;
    const int n = bid >> 8, oh = bid & 255;
    const int ow = t;
    const int khA = (oh + 1) & 1, ihA = (oh + 1) >> 1;
    const int kwA = (ow + 1) & 1, iwA = (ow + 1) >> 1;

    float a0 = tb2[0], a1 = tb2[1], a2 = tb2[2];
    #pragma unroll
    for (int a = 0; a < 2; ++a) {
        const int ih = ihA - a;
        if ((unsigned)ih >= 128u) continue;
        const int kh = khA + 2 * a;
        #pragma unroll
        for (int b = 0; b < 2; ++b) {
            const int iw = iwA - b;
            if ((unsigned)iw >= 128u) continue;
            const int kw = kwA + 2 * b;
            const ushort* src = in + (((long long)(n * 128 + ih)) * 128 + iw) * 64;
            const int k = kh * 4 + kw;
            #pragma unroll
            for (int c8 = 0; c8 < 8; ++c8) {
                uint4 v = *reinterpret_cast<const uint4*>(src + c8 * 8);
                const uint u[4] = {v.x, v.y, v.z, v.w};
                #pragma unroll
                for (int p = 0; p < 4; ++p) {
                    union { uint i; float f; } lo, hi;
                    lo.i = u[p] << 16; hi.i = u[p] & 0xFFFF0000u;
                    const int ci = c8 * 8 + p * 2;
                    a0 = fmaf(lo.f, sW[ci * 48 + 0 * 16 + k], a0);
                    a1 = fmaf(lo.f, sW[ci * 48 + 1 * 16 + k], a1);
                    a2 = fmaf(lo.f, sW[ci * 48 + 2 * 16 + k], a2);
                    a0 = fmaf(hi.f, sW[(ci + 1) * 48 + 0 * 16 + k], a0);
                    a1 = fmaf(hi.f, sW[(ci + 1) * 48 + 1 * 16 + k], a1);
                    a2 = fmaf(hi.f, sW[(ci + 1) * 48 + 2 * 16 + k], a2);
                }
            }
        }
    }
    const long long px = (long long)oh * 256 + ow;
    out[(long long)(n * 3 + 0) * 65536 + px] = a0;
    out[(long long)(n * 3 + 1) * 65536 + px] = a1;
    out[(long long)(n * 3 + 2) * 65536 + px] = a2;
}

// ---------------------------------------------------------------------------
// MFMA VQ (unchanged).
// ---------------------------------------------------------------------------
__global__ __launch_bounds__(256)
void vq_mfma(const ushort* __restrict__ z, const ushort* __restrict__ Ebf,
             const float* __restrict__ E, const float* __restrict__ eN,
             ushort* __restrict__ zq, float* __restrict__ stats) {
    __shared__ ushort sZ[64 * 72];
    __shared__ float sEN[512];
    __shared__ float sV[64 * 4];
    __shared__ int   sI[64 * 4];
    __shared__ int   sIdx[64];
    __shared__ unsigned shist[512];
    __shared__ float red[256];

    const int t = threadIdx.x;
    const int w = t >> 6, l = t & 63;
    const long long p0 = (long long)blockIdx.x * 64;

    {
        const int px = t >> 2, koff = (t & 3) * 16;
        const ushort* p = z + (p0 + px) * 64 + koff;
        uint4 a0 = *reinterpret_cast<const uint4*>(p);
        uint4 a1 = *reinterpret_cast<const uint4*>(p + 8);
        *reinterpret_cast<uint4*>(&sZ[px * 72 + koff])     = a0;
        *reinterpret_cast<uint4*>(&sZ[px * 72 + koff + 8]) = a1;
        sEN[t] = eN[t]; sEN[t + 256] = eN[t + 256];
        shist[t] = 0u; shist[t + 256] = 0u;
    }
    __syncthreads();

    f32x4 acc[4][8] = {};
    #pragma unroll
    for (int ks = 0; ks < 2; ++ks) {
        bf16x8 bfr[8];
        #pragma unroll
        for (int nf = 0; nf < 8; ++nf)
            bfr[nf] = *reinterpret_cast<const bf16x8*>(
                Ebf + (w * 128 + nf * 16 + (l & 15)) * 64 + ks * 32 + ((l >> 4) * 8));
        #pragma unroll
        for (int mf = 0; mf < 4; ++mf) {
            bf16x8 afr = *reinterpret_cast<const bf16x8*>(
                &sZ[(mf * 16 + (l & 15)) * 72 + ks * 32 + ((l >> 4) * 8)]);
            #pragma unroll
            for (int nf = 0; nf < 8; ++nf)
                acc[mf][nf] = __builtin_amdgcn_mfma_f32_16x16x32_bf16(
                    afr, bfr[nf], acc[mf][nf], 0, 0, 0);
        }
    }

    float eNr[8];
    #pragma unroll
    for (int nf = 0; nf < 8; ++nf) eNr[nf] = sEN[w * 128 + nf * 16 + (l & 15)];

    #pragma unroll
    for (int mf = 0; mf < 4; ++mf) {
        #pragma unroll
        for (int r = 0; r < 4; ++r) {
            float best = 3.4e38f; int bidx = 0;
            #pragma unroll
            for (int nf = 0; nf < 8; ++nf) {
                float s = eNr[nf] - 2.f * acc[mf][nf][r];
                int   c = w * 128 + nf * 16 + (l & 15);
                if (s < best || (s == best && c < bidx)) { best = s; bidx = c; }
            }
            #pragma unroll
            for (int off = 1; off < 16; off <<= 1) {
                float ov = __shfl_xor(best, off);
                int   oi = __shfl_xor(bidx, off);
                if (ov < best || (ov == best && oi < bidx)) { best = ov; bidx = oi; }
            }
            if ((l & 15) == 0) {
                const int px = mf * 16 + ((l >> 4) * 4) + r;
                sV[px * 4 + w] = best; sI[px * 4 + w] = bidx;
            }
        }
    }
    __syncthreads();

    if (t < 64) {
        float best = sV[t * 4]; int bidx = sI[t * 4];
        #pragma unroll
        for (int w2 = 1; w2 < 4; ++w2) {
            float v = sV[t * 4 + w2]; int c = sI[t * 4 + w2];
            if (v < best || (v == best && c < bidx)) { best = v; bidx = c; }
        }
        sIdx[t] = bidx;
        atomicAdd(&shist[bidx], 1u);
    }
    __syncthreads();

    {
        const int px = t >> 2, doff = (t & 3) * 16;
        const int idx = sIdx[px];
        const float* e = E + idx * 64 + doff;
        float dist = 0.f;
        uint4 pk4[2];
        ushort* pk = reinterpret_cast<ushort*>(pk4);
        #pragma unroll
        for (int j = 0; j < 16; ++j) {
            float ev = e[j];
            float zv = bf2f(sZ[px * 72 + doff + j]);
            float df = ev - zv;
            dist = fmaf(df, df, dist);
            pk[j] = f2bf(ev);
        }
        *reinterpret_cast<uint4*>(zq + (p0 + px) * 64 + doff)     = pk4[0];
        *reinterpret_cast<uint4*>(zq + (p0 + px) * 64 + doff + 8) = pk4[1];
        red[t] = dist;
    }
    __syncthreads();
    for (int s = 128; s > 0; s >>= 1) {
        if (t < s) red[t] += red[t + s];
        __syncthreads();
    }
    if (t == 0) atomicAdd(&stats[0], red[0]);
    for (int i = t; i < 512; i += 256) {
        unsigned c = shist[i];
        if (c) atomicAdd(&stats[1 + i], (float)c);
    }
}

__global__ __launch_bounds__(512)
void finalize_kernel(const float* __restrict__ stats, float* __restrict__ out, int plast) {
    __shared__ float red[512];
    int t = threadIdx.x;
    float c = stats[1 + t];
    float p = c * (1.f / 131072.f);
    red[t] = p * logf(p + 1e-10f);
    __syncthreads();
    for (int s = 256; s > 0; s >>= 1) {
        if (t < s) red[t] += red[t + s];
        __syncthreads();
    }
    if (t == 0) {
        out[plast] = expf(-red[0]);
        out[0] = 7.6f * stats[0] * (1.f / 8388608.f);
    }
}

// ---------------------------------------------------------------------------
extern "C" void kernel_launch(void* const* d_in, const int* in_sizes, int n_in,
                              void* d_out, int out_size, void* d_ws, size_t ws_size,
                              hipStream_t stream) {
    (void)in_sizes; (void)n_in; (void)ws_size;
    const float* x   = (const float*)d_in[0];
    const float* w1  = (const float*)d_in[1];
    const float* b1  = (const float*)d_in[2];
    const float* w2  = (const float*)d_in[3];
    const float* b2  = (const float*)d_in[4];
    const float* w3  = (const float*)d_in[5];
    const float* b3  = (const float*)d_in[6];
    const float* r0a = (const float*)d_in[7];
    const float* r0b = (const float*)d_in[8];
    const float* r1a = (const float*)d_in[9];
    const float* r1b = (const float*)d_in[10];
    const float* wp  = (const float*)d_in[11];
    const float* bp  = (const float*)d_in[12];
    const float* E   = (const float*)d_in[13];
    const float* dw1 = (const float*)d_in[14];
    const float* db1 = (const float*)d_in[15];
    const float* dr0a= (const float*)d_in[16];
    const float* dr0b= (const float*)d_in[17];
    const float* dr1a= (const float*)d_in[18];
    const float* dr1b= (const float*)d_in[19];
    const float* tw1 = (const float*)d_in[20];
    const float* tb1 = (const float*)d_in[21];
    const float* tw2 = (const float*)d_in[22];
    const float* tb2 = (const float*)d_in[23];

    float* out = (float*)d_out;
    ushort* ws = (ushort*)d_ws;

    ushort* H1 = ws;                  // [32,128,128,64] ; later convT1 out T
    ushort* H2 = ws + 33554432;       // [32,64,64,128]  ; later decoder D
    ushort* C  = ws + 50331648;       // [32,64,64,128]
    ushort* F  = ws + 67108864;       // [32,64,64,32]  res temp
    ushort* Z  = ws + 71303168;       // [131072,64]
    ushort* ZQ = ws + 79691776;       // [131072,64]
    ushort* W0 = ws + 88080384;       // weight block
    ushort* Wt2   = W0;               // 131072
    ushort* Wt3   = W0 + 131072;      // 147456
    ushort* Wr0a  = W0 + 278528;
    ushort* Wr0b  = W0 + 315392;
    ushort* Wr1a  = W0 + 352256;
    ushort* Wr1b  = W0 + 389120;
    ushort* Wp    = W0 + 425984;
    ushort* Wd1   = W0 + 434176;
    ushort* Wdr0a = W0 + 507904;
    ushort* Wdr0b = W0 + 544768;
    ushort* Wdr1a = W0 + 581632;
    ushort* Wdr1b = W0 + 618496;
    ushort* WT1   = W0 + 655360;      // 131072 -> ends W0+786432
    ushort* Ebf   = W0 + 786432;      // 32768
    float*  eN    = (float*)(W0 + 819200);   // 512 floats
    float*  ST    = (float*)(W0 + 820224);   // 513 floats -> ends W0+821250
    ushort* Wc1   = W0 + 822272;      // 4096 bf16 conv1 weights
    ushort* T = H1;
    ushort* D = H2;

    hipMemsetAsync(ST, 0, 513 * sizeof(float), stream);

    dim3 blk(256);
    // ---- all prep in one launch ----
    wt_all<<<3216, blk, 0, stream>>>(w2, Wt2, w3, Wt3, r0a, Wr0a, r0b, Wr0b,
                                     r1a, Wr1a, r1b, Wr1b, wp, Wp, dw1, Wd1,
                                     dr0a, Wdr0a, dr0b, Wdr0b, dr1a, Wdr1a, dr1b, Wdr1b,
                                     tw1, WT1, E, Ebf, eN, w1, Wc1);

    // ---- encoder ----
    conv1_mfma<<<4096, blk, 0, stream>>>(x, Wc1, b1, H1);
    conv_s2<64,128,true><<<1024, blk, 0, stream>>>(H1, Wt2, b2, H2, 128, 128);
    conv_lds<128,128,9,1,false,false,false><<<1024, blk, 0, stream>>>(H2, Wt3, b3, nullptr, C);
    conv_lds<128, 32,9,1,true ,true ,false><<<1024, blk, 0, stream>>>(C, Wr0a, nullptr, nullptr, F);
    conv_lds<32, 128,9,1,false,false,true ><<<1024, blk, 0, stream>>>(F, Wr0b, nullptr, C, C);
    conv_lds<128, 32,9,1,true ,true ,false><<<1024, blk, 0, stream>>>(C, Wr1a, nullptr, nullptr, F);
    conv_lds<32, 128,9,1,false,true ,true ><<<1024, blk, 0, stream>>>(F, Wr1b, nullptr, C, C);
    conv_lds<128, 64,1,0,false,false,false><<<1024, blk, 0, stream>>>(C, Wp, bp, nullptr, Z);

    // ---- VQ ----
    vq_mfma<<<2048, blk, 0, stream>>>(Z, Ebf, E, eN, ZQ, ST);

    // ---- decoder ----
    conv_lds<64, 128,9,1,false,false,false><<<1024, blk, 0, stream>>>(ZQ, Wd1, db1, nullptr, D);
    conv_lds<128, 32,9,1,true ,true ,false><<<1024, blk, 0, stream>>>(D, Wdr0a, nullptr, nullptr, F);
    conv_lds<32, 128,9,1,false,false,true ><<<1024, blk, 0, stream>>>(F, Wdr0b, nullptr, D, D);
    conv_lds<128, 32,9,1,true ,true ,false><<<1024, blk, 0, stream>>>(D, Wdr1a, nullptr, nullptr, F);
    conv_lds<32, 128,9,1,false,true ,true ><<<1024, blk, 0, stream>>>(F, Wdr1b, nullptr, D, D);
    convt1_lds<<<1024, blk, 0, stream>>>(D, WT1, tb1, T);
    convt2_k<<<32 * 256, blk, 0, stream>>>(T, tw2, tb2, out + 1);

    // ---- loss / perplexity ----
    finalize_kernel<<<1, 512, 0, stream>>>(ST, out, out_size - 1);
}